// Round 5
// baseline (635.296 us; speedup 1.0000x reference)
//
#include <hip/hip_runtime.h>

#define N_NODES 20000
#define N_EDGES 320000
#define IN_F    168
#define HID     256

// ---------------- graph prep ----------------

__global__ void edge_count_deg(const int* __restrict__ ei, const float* __restrict__ ew,
                               float* __restrict__ deg, int* __restrict__ counts) {
    int e = blockIdx.x * blockDim.x + threadIdx.x;
    if (e >= N_EDGES) return;
    int d = ei[N_EDGES + e];            // dst row of edge_index
    atomicAdd(&deg[d], ew[e]);
    atomicAdd(&counts[d], 1);
}

// single-block: exclusive scan over counts -> offs (n+1), wave-shuffle based.
// Also folds deg -> dinv = rsqrt(deg+1)  (deg complete before this launch).
__global__ void scan_counts(const int* __restrict__ counts, int* __restrict__ offs,
                            float* __restrict__ deg, int n) {
    int tid  = threadIdx.x;
    int lane = tid & 63;
    int wv   = tid >> 6;                // 16 waves
    __shared__ int wsum[16];
    __shared__ int s_total;
    __shared__ int s_carry;
    if (tid == 0) s_carry = 0;
    __syncthreads();
    for (int base = 0; base < n; base += 1024) {
        int i = base + tid;
        if (i < n) deg[i] = rsqrtf(deg[i] + 1.0f);   // self-loop weight 1.0
        int v = (i < n) ? counts[i] : 0;
        int incl = v;
        #pragma unroll
        for (int d = 1; d < 64; d <<= 1) {
            int t = __shfl_up(incl, d);
            if (lane >= d) incl += t;
        }
        if (lane == 63) wsum[wv] = incl;
        __syncthreads();
        if (wv == 0) {
            int w = (lane < 16) ? wsum[lane] : 0;
            int winc = w;
            #pragma unroll
            for (int d = 1; d < 16; d <<= 1) {
                int t = __shfl_up(winc, d);
                if (lane >= d) winc += t;
            }
            if (lane < 16) wsum[lane] = winc - w;   // exclusive wave offsets
            if (lane == 15) s_total = winc;         // chunk total
        }
        __syncthreads();
        int c = s_carry;
        if (i < n) offs[i] = c + wsum[wv] + incl - v;
        __syncthreads();
        if (tid == 0) s_carry = c + s_total;
        __syncthreads();
    }
    if (tid == 0) offs[n] = s_carry;
}

__global__ void scatter_edges(const int* __restrict__ ei, const float* __restrict__ ew,
                              const float* __restrict__ dinv, const int* __restrict__ offs,
                              int* __restrict__ cursor, int* __restrict__ csr_src,
                              float* __restrict__ csr_norm) {
    int e = blockIdx.x * blockDim.x + threadIdx.x;
    if (e >= N_EDGES) return;
    int s = ei[e];
    int d = ei[N_EDGES + e];
    int pos = offs[d] + atomicAdd(&cursor[d], 1);
    csr_src[pos]  = s;
    csr_norm[pos] = dinv[s] * ew[e] * dinv[d];
}

// ---------------- SGEMM: C[M,256] = A[M,K] * W[256,K]^T ----------------
// WAVE-BLOCK version: 64 threads (one wave) per block, 64x64 tile, 8x8 microtile.
// Single-wave block => __syncthreads has no s_barrier (no inter-wave convoy).
// 2 FLOP per LDS byte read (vs 1.0 at 4x4) => LDS-BW ceiling ~110 TF.
// LDS row stride 72 floats (288B, 16B-aligned): staging writes 2-way (free),
// fragment reads 8 addrs over 4 bank-quads = 2-way (free).

#define BM 64
#define BN 64
#define BK 8
#define LDT 72

__global__ __launch_bounds__(64, 4) void sgemm_nt(const float* __restrict__ A,
                                                  const float* __restrict__ W,
                                                  float* __restrict__ C,
                                                  int M, int K) {
    __shared__ __align__(16) float As[BK][LDT];
    __shared__ __align__(16) float Ws[BK][LDT];
    const int tid = threadIdx.x;           // 0..63
    const int bm = blockIdx.x * BM;
    const int bn = blockIdx.y * BN;
    const int tx = (tid & 7) * 8;          // col group
    const int ty = (tid >> 3) * 8;         // row group
    const int gm = bm + tid;               // A staging row
    const int gn = bn + tid;               // W staging row (always < 256)
    float acc[8][8] = {};

    const int niter = K / BK;              // K % 8 == 0 for both layers
    const float4 z4 = make_float4(0.f, 0.f, 0.f, 0.f);

    // prefetch tile 0 into registers (8 floats of A-row, 8 of W-row per thread)
    float4 pa0 = (gm < M) ? *(const float4*)&A[(size_t)gm * K + 0] : z4;
    float4 pa1 = (gm < M) ? *(const float4*)&A[(size_t)gm * K + 4] : z4;
    float4 pw0 = *(const float4*)&W[(size_t)gn * K + 0];
    float4 pw1 = *(const float4*)&W[(size_t)gn * K + 4];

    for (int it = 0; it < niter; ++it) {
        As[0][tid] = pa0.x; As[1][tid] = pa0.y; As[2][tid] = pa0.z; As[3][tid] = pa0.w;
        As[4][tid] = pa1.x; As[5][tid] = pa1.y; As[6][tid] = pa1.z; As[7][tid] = pa1.w;
        Ws[0][tid] = pw0.x; Ws[1][tid] = pw0.y; Ws[2][tid] = pw0.z; Ws[3][tid] = pw0.w;
        Ws[4][tid] = pw1.x; Ws[5][tid] = pw1.y; Ws[6][tid] = pw1.z; Ws[7][tid] = pw1.w;
        __syncthreads();                   // single wave: waitcnt only
        if (it + 1 < niter) {              // uniform branch; loads issue before compute
            int k = (it + 1) * BK;
            pa0 = (gm < M) ? *(const float4*)&A[(size_t)gm * K + k] : z4;
            pa1 = (gm < M) ? *(const float4*)&A[(size_t)gm * K + k + 4] : z4;
            pw0 = *(const float4*)&W[(size_t)gn * K + k];
            pw1 = *(const float4*)&W[(size_t)gn * K + k + 4];
        }
        #pragma unroll
        for (int k = 0; k < BK; ++k) {
            float4 a0 = *(const float4*)&As[k][ty];
            float4 a1 = *(const float4*)&As[k][ty + 4];
            float4 b0 = *(const float4*)&Ws[k][tx];
            float4 b1 = *(const float4*)&Ws[k][tx + 4];
            float av[8] = {a0.x, a0.y, a0.z, a0.w, a1.x, a1.y, a1.z, a1.w};
            float bv[8] = {b0.x, b0.y, b0.z, b0.w, b1.x, b1.y, b1.z, b1.w};
            #pragma unroll
            for (int i = 0; i < 8; ++i)
                #pragma unroll
                for (int j = 0; j < 8; ++j)
                    acc[i][j] += av[i] * bv[j];
        }
        __syncthreads();                   // protect As/Ws before next overwrite
    }

    #pragma unroll
    for (int i = 0; i < 8; ++i) {
        int row = bm + ty + i;
        if (row < M) {
            float4 v0 = make_float4(acc[i][0], acc[i][1], acc[i][2], acc[i][3]);
            float4 v1 = make_float4(acc[i][4], acc[i][5], acc[i][6], acc[i][7]);
            *(float4*)&C[(size_t)row * HID + bn + tx]     = v0;
            *(float4*)&C[(size_t)row * HID + bn + tx + 4] = v1;
        }
    }
}

// ---------------- aggregation (+self-loop, +bias, ReLU) ----------------
// one WAVE per dst node; 64 lanes x float4 = one 1KB row per load issue; 4 rows in flight

__global__ __launch_bounds__(256) void aggregate4(const float4* __restrict__ xw4,
                                                  const float* __restrict__ dinv,
                                                  const int* __restrict__ offs,
                                                  const int* __restrict__ csr_src,
                                                  const float* __restrict__ csr_norm,
                                                  const float4* __restrict__ bias4,
                                                  float4* __restrict__ out4) {
    int wave = threadIdx.x >> 6;
    int lane = threadIdx.x & 63;
    int n = blockIdx.x * 4 + wave;      // N_NODES % 4 == 0
    float di = dinv[n];
    float sw = di * di;
    float4 v = xw4[(size_t)n * 64 + lane];
    float ax = sw * v.x, ay = sw * v.y, az = sw * v.z, aw = sw * v.w;

    int p0 = offs[n], p1 = offs[n + 1];
    int p = p0;
    for (; p + 4 <= p1; p += 4) {
        int   s0 = csr_src[p],     s1 = csr_src[p + 1];
        int   s2 = csr_src[p + 2], s3 = csr_src[p + 3];
        float w0 = csr_norm[p],     w1 = csr_norm[p + 1];
        float w2 = csr_norm[p + 2], w3 = csr_norm[p + 3];
        float4 r0 = xw4[(size_t)s0 * 64 + lane];
        float4 r1 = xw4[(size_t)s1 * 64 + lane];
        float4 r2 = xw4[(size_t)s2 * 64 + lane];
        float4 r3 = xw4[(size_t)s3 * 64 + lane];
        ax += w0 * r0.x + w1 * r1.x + w2 * r2.x + w3 * r3.x;
        ay += w0 * r0.y + w1 * r1.y + w2 * r2.y + w3 * r3.y;
        az += w0 * r0.z + w1 * r1.z + w2 * r2.z + w3 * r3.z;
        aw += w0 * r0.w + w1 * r1.w + w2 * r2.w + w3 * r3.w;
    }
    for (; p < p1; ++p) {
        int   s0 = csr_src[p];
        float w0 = csr_norm[p];
        float4 r0 = xw4[(size_t)s0 * 64 + lane];
        ax += w0 * r0.x; ay += w0 * r0.y; az += w0 * r0.z; aw += w0 * r0.w;
    }

    float4 b = bias4[lane];
    ax += b.x; ay += b.y; az += b.z; aw += b.w;
    float4 o;
    o.x = ax > 0.f ? ax : 0.f;
    o.y = ay > 0.f ? ay : 0.f;
    o.z = az > 0.f ? az : 0.f;
    o.w = aw > 0.f ? aw : 0.f;
    out4[(size_t)n * 64 + lane] = o;
}

// ---------------- launch ----------------

extern "C" void kernel_launch(void* const* d_in, const int* in_sizes, int n_in,
                              void* d_out, int out_size, void* d_ws, size_t ws_size,
                              hipStream_t stream) {
    const float* x  = (const float*)d_in[0];
    const int*   ei = (const int*)d_in[1];
    const float* ew = (const float*)d_in[2];
    const float* W1 = (const float*)d_in[3];
    const float* b1 = (const float*)d_in[4];
    const float* W2 = (const float*)d_in[5];
    const float* b2 = (const float*)d_in[6];
    float* out = (float*)d_out;

    char* ws = (char*)d_ws;
    float* deg      = (float*)(ws);                         // 20000 f32  (becomes dinv)
    int*   counts   = (int*)(ws + 80000);                   // 20000 i32
    int*   cursor   = (int*)(ws + 160000);                  // 20000 i32
    int*   offs     = (int*)(ws + 240000);                  // 20001 i32 (pad to 80016)
    int*   csr_src  = (int*)(ws + 320016);                  // 320000 i32
    float* csr_norm = (float*)(ws + 1600016);               // 320000 f32
    float* xw       = (float*)(ws + 2880016);               // 20000x256 f32
    float* h1       = (float*)(ws + 23360016);              // 20000x256 f32

    hipMemsetAsync(d_ws, 0, 240000, stream);

    const int TB = 256;
    edge_count_deg<<<(N_EDGES + TB - 1) / TB, TB, 0, stream>>>(ei, ew, deg, counts);
    scan_counts<<<1, 1024, 0, stream>>>(counts, offs, deg, N_NODES);
    scatter_edges<<<(N_EDGES + TB - 1) / TB, TB, 0, stream>>>(ei, ew, deg, offs, cursor,
                                                              csr_src, csr_norm);

    dim3 g1((N_NODES + BM - 1) / BM, HID / BN);
    // layer 1
    sgemm_nt<<<g1, 64, 0, stream>>>(x, W1, xw, N_NODES, IN_F);
    aggregate4<<<N_NODES / 4, 256, 0, stream>>>((const float4*)xw, deg, offs, csr_src,
                                                csr_norm, (const float4*)b1, (float4*)h1);
    // layer 2
    sgemm_nt<<<g1, 64, 0, stream>>>(h1, W2, xw, N_NODES, HID);
    aggregate4<<<N_NODES / 4, 256, 0, stream>>>((const float4*)xw, deg, offs, csr_src,
                                                csr_norm, (const float4*)b2, (float4*)out);
}

// Round 6
// 507.120 us; speedup vs baseline: 1.2528x; 1.2528x over previous
//
#include <hip/hip_runtime.h>

#define N_NODES 20000
#define N_EDGES 320000
#define IN_F    168
#define HID     256

typedef __attribute__((ext_vector_type(8))) short bf16x8;
typedef __attribute__((ext_vector_type(4))) float f32x4;

// fp32 -> bf16 (round-to-nearest-even), bit pattern as short
__device__ __forceinline__ short f2bf(float f) {
    union { float f; unsigned u; } v; v.f = f;
    unsigned r = v.u + 0x7FFFu + ((v.u >> 16) & 1u);
    return (short)(r >> 16);
}
__device__ __forceinline__ float bf2f(short s) {
    union { unsigned u; float f; } v; v.u = ((unsigned)(unsigned short)s) << 16;
    return v.f;
}

// ---------------- graph prep ----------------

__global__ void edge_count_deg(const int* __restrict__ ei, const float* __restrict__ ew,
                               float* __restrict__ deg, int* __restrict__ counts) {
    int e = blockIdx.x * blockDim.x + threadIdx.x;
    if (e >= N_EDGES) return;
    int d = ei[N_EDGES + e];            // dst row of edge_index
    atomicAdd(&deg[d], ew[e]);
    atomicAdd(&counts[d], 1);
}

// single-block: exclusive scan over counts -> offs (n+1), wave-shuffle based.
// Also folds deg -> dinv = rsqrt(deg+1).
__global__ void scan_counts(const int* __restrict__ counts, int* __restrict__ offs,
                            float* __restrict__ deg, int n) {
    int tid  = threadIdx.x;
    int lane = tid & 63;
    int wv   = tid >> 6;                // 16 waves
    __shared__ int wsum[16];
    __shared__ int s_total;
    __shared__ int s_carry;
    if (tid == 0) s_carry = 0;
    __syncthreads();
    for (int base = 0; base < n; base += 1024) {
        int i = base + tid;
        if (i < n) deg[i] = rsqrtf(deg[i] + 1.0f);   // self-loop weight 1.0
        int v = (i < n) ? counts[i] : 0;
        int incl = v;
        #pragma unroll
        for (int d = 1; d < 64; d <<= 1) {
            int t = __shfl_up(incl, d);
            if (lane >= d) incl += t;
        }
        if (lane == 63) wsum[wv] = incl;
        __syncthreads();
        if (wv == 0) {
            int w = (lane < 16) ? wsum[lane] : 0;
            int winc = w;
            #pragma unroll
            for (int d = 1; d < 16; d <<= 1) {
                int t = __shfl_up(winc, d);
                if (lane >= d) winc += t;
            }
            if (lane < 16) wsum[lane] = winc - w;   // exclusive wave offsets
            if (lane == 15) s_total = winc;         // chunk total
        }
        __syncthreads();
        int c = s_carry;
        if (i < n) offs[i] = c + wsum[wv] + incl - v;
        __syncthreads();
        if (tid == 0) s_carry = c + s_total;
        __syncthreads();
    }
    if (tid == 0) offs[n] = s_carry;
}

__global__ void scatter_edges(const int* __restrict__ ei, const float* __restrict__ ew,
                              const float* __restrict__ dinv, const int* __restrict__ offs,
                              int* __restrict__ cursor, int* __restrict__ csr_src,
                              float* __restrict__ csr_norm) {
    int e = blockIdx.x * blockDim.x + threadIdx.x;
    if (e >= N_EDGES) return;
    int s = ei[e];
    int d = ei[N_EDGES + e];
    int pos = offs[d] + atomicAdd(&cursor[d], 1);
    csr_src[pos]  = s;
    csr_norm[pos] = dinv[s] * ew[e] * dinv[d];
}

// ---------------- MFMA GEMM: C[M,256] = A[M,K] * W[256,K]^T ----------------
// Split-bf16 (Markidis): A*W ~= Ah*Wh + Ah*Wl + Al*Wh, fp32 accumulate in MFMA.
// One wave computes one 16x16 tile with mfma_f32_16x16x32_bf16 over K.
// Fragment layout (m89/m120-verified): A[m=lane&15][k=quad*8+j],
// B[n=lane&15][k=quad*8+j] (W stored [N,K] row-major == B^T), C/D col=lane&15,
// row=quad*4+reg. M=20000 -> 1250 exact tiles, no row bounds checks.
// Block = 4 waves covering 4 consecutive nt of the same mt (A-frag L1 reuse).

__device__ __forceinline__ void split8(const float4& v0, const float4& v1,
                                       bf16x8& hi, bf16x8& lo) {
    float a[8] = {v0.x, v0.y, v0.z, v0.w, v1.x, v1.y, v1.z, v1.w};
    #pragma unroll
    for (int i = 0; i < 8; ++i) {
        short h = f2bf(a[i]);
        hi[i] = h;
        lo[i] = f2bf(a[i] - bf2f(h));
    }
}

// Layer-1 style: A fp32 [M,K] (K=168, padded to Ksteps*32 with zero octets)
__global__ __launch_bounds__(256) void mfma_gemm_f32a(const float* __restrict__ A,
                                                      const float* __restrict__ W,
                                                      float* __restrict__ C,
                                                      int K, int Ksteps) {
    const int wv   = threadIdx.x >> 6;
    const int lane = threadIdx.x & 63;
    const int mt   = blockIdx.x >> 2;          // 0..1249
    const int nt   = (blockIdx.x & 3) * 4 + wv;// 0..15
    const int l16  = lane & 15;
    const int quad = lane >> 4;
    const int kb   = quad * 8;

    const float* arow = A + (size_t)(mt * 16 + l16) * K;
    const float* wrow = W + (size_t)(nt * 16 + l16) * K;

    f32x4 acc = {0.f, 0.f, 0.f, 0.f};
    const float4 z4 = make_float4(0.f, 0.f, 0.f, 0.f);

    for (int ks = 0; ks < Ksteps; ++ks) {
        int k = ks * 32 + kb;
        bool val = (k + 8 <= K);               // octet fully valid or fully zero
        float4 a0 = val ? *(const float4*)(arow + k)     : z4;
        float4 a1 = val ? *(const float4*)(arow + k + 4) : z4;
        float4 w0 = val ? *(const float4*)(wrow + k)     : z4;
        float4 w1 = val ? *(const float4*)(wrow + k + 4) : z4;
        bf16x8 ah, al, wh, wl;
        split8(a0, a1, ah, al);
        split8(w0, w1, wh, wl);
        acc = __builtin_amdgcn_mfma_f32_16x16x32_bf16(ah, wh, acc, 0, 0, 0);
        acc = __builtin_amdgcn_mfma_f32_16x16x32_bf16(ah, wl, acc, 0, 0, 0);
        acc = __builtin_amdgcn_mfma_f32_16x16x32_bf16(al, wh, acc, 0, 0, 0);
    }

    float* crow = C + (size_t)(mt * 16 + quad * 4) * HID + nt * 16 + l16;
    #pragma unroll
    for (int r = 0; r < 4; ++r)
        crow[(size_t)r * HID] = acc[r];
}

// Layer-2 style: A pre-split bf16 (Ah, Al) [M,256]
__global__ __launch_bounds__(256) void mfma_gemm_bf16a(const short* __restrict__ Ah,
                                                       const short* __restrict__ Al,
                                                       const float* __restrict__ W,
                                                       float* __restrict__ C) {
    const int K = HID;                         // 256
    const int wv   = threadIdx.x >> 6;
    const int lane = threadIdx.x & 63;
    const int mt   = blockIdx.x >> 2;
    const int nt   = (blockIdx.x & 3) * 4 + wv;
    const int l16  = lane & 15;
    const int quad = lane >> 4;
    const int kb   = quad * 8;

    const short* ahrow = Ah + (size_t)(mt * 16 + l16) * K;
    const short* alrow = Al + (size_t)(mt * 16 + l16) * K;
    const float* wrow  = W  + (size_t)(nt * 16 + l16) * K;

    f32x4 acc = {0.f, 0.f, 0.f, 0.f};

    #pragma unroll 2
    for (int ks = 0; ks < 8; ++ks) {
        int k = ks * 32 + kb;
        bf16x8 ah = *(const bf16x8*)(ahrow + k);
        bf16x8 al = *(const bf16x8*)(alrow + k);
        float4 w0 = *(const float4*)(wrow + k);
        float4 w1 = *(const float4*)(wrow + k + 4);
        bf16x8 wh, wl;
        split8(w0, w1, wh, wl);
        acc = __builtin_amdgcn_mfma_f32_16x16x32_bf16(ah, wh, acc, 0, 0, 0);
        acc = __builtin_amdgcn_mfma_f32_16x16x32_bf16(ah, wl, acc, 0, 0, 0);
        acc = __builtin_amdgcn_mfma_f32_16x16x32_bf16(al, wh, acc, 0, 0, 0);
    }

    float* crow = C + (size_t)(mt * 16 + quad * 4) * HID + nt * 16 + l16;
    #pragma unroll
    for (int r = 0; r < 4; ++r)
        crow[(size_t)r * HID] = acc[r];
}

// ---------------- aggregation (+self-loop, +bias, ReLU) ----------------
// one WAVE per dst node; 64 lanes x float4 = one 1KB row per load issue.
// Layer-1 variant emits split bf16 (h1h, h1l) for the layer-2 MFMA GEMM.

__device__ __forceinline__ void agg_body(const float4* __restrict__ xw4,
                                         const float* __restrict__ dinv,
                                         const int* __restrict__ offs,
                                         const int* __restrict__ csr_src,
                                         const float* __restrict__ csr_norm,
                                         const float4* __restrict__ bias4,
                                         int n, int lane, float4& o) {
    float di = dinv[n];
    float sw = di * di;
    float4 v = xw4[(size_t)n * 64 + lane];
    float ax = sw * v.x, ay = sw * v.y, az = sw * v.z, aw = sw * v.w;

    int p0 = offs[n], p1 = offs[n + 1];
    int p = p0;
    for (; p + 4 <= p1; p += 4) {
        int   s0 = csr_src[p],     s1 = csr_src[p + 1];
        int   s2 = csr_src[p + 2], s3 = csr_src[p + 3];
        float w0 = csr_norm[p],     w1 = csr_norm[p + 1];
        float w2 = csr_norm[p + 2], w3 = csr_norm[p + 3];
        float4 r0 = xw4[(size_t)s0 * 64 + lane];
        float4 r1 = xw4[(size_t)s1 * 64 + lane];
        float4 r2 = xw4[(size_t)s2 * 64 + lane];
        float4 r3 = xw4[(size_t)s3 * 64 + lane];
        ax += w0 * r0.x + w1 * r1.x + w2 * r2.x + w3 * r3.x;
        ay += w0 * r0.y + w1 * r1.y + w2 * r2.y + w3 * r3.y;
        az += w0 * r0.z + w1 * r1.z + w2 * r2.z + w3 * r3.z;
        aw += w0 * r0.w + w1 * r1.w + w2 * r2.w + w3 * r3.w;
    }
    for (; p < p1; ++p) {
        int   s0 = csr_src[p];
        float w0 = csr_norm[p];
        float4 r0 = xw4[(size_t)s0 * 64 + lane];
        ax += w0 * r0.x; ay += w0 * r0.y; az += w0 * r0.z; aw += w0 * r0.w;
    }

    float4 b = bias4[lane];
    ax += b.x; ay += b.y; az += b.z; aw += b.w;
    o.x = ax > 0.f ? ax : 0.f;
    o.y = ay > 0.f ? ay : 0.f;
    o.z = az > 0.f ? az : 0.f;
    o.w = aw > 0.f ? aw : 0.f;
}

__global__ __launch_bounds__(256) void aggregate_out(const float4* __restrict__ xw4,
                                                     const float* __restrict__ dinv,
                                                     const int* __restrict__ offs,
                                                     const int* __restrict__ csr_src,
                                                     const float* __restrict__ csr_norm,
                                                     const float4* __restrict__ bias4,
                                                     float4* __restrict__ out4) {
    int wave = threadIdx.x >> 6;
    int lane = threadIdx.x & 63;
    int n = blockIdx.x * 4 + wave;      // N_NODES % 4 == 0
    float4 o;
    agg_body(xw4, dinv, offs, csr_src, csr_norm, bias4, n, lane, o);
    out4[(size_t)n * 64 + lane] = o;
}

__global__ __launch_bounds__(256) void aggregate_split(const float4* __restrict__ xw4,
                                                       const float* __restrict__ dinv,
                                                       const int* __restrict__ offs,
                                                       const int* __restrict__ csr_src,
                                                       const float* __restrict__ csr_norm,
                                                       const float4* __restrict__ bias4,
                                                       short* __restrict__ h1h,
                                                       short* __restrict__ h1l) {
    int wave = threadIdx.x >> 6;
    int lane = threadIdx.x & 63;
    int n = blockIdx.x * 4 + wave;
    float4 o;
    agg_body(xw4, dinv, offs, csr_src, csr_norm, bias4, n, lane, o);
    float a[4] = {o.x, o.y, o.z, o.w};
    short hv[4], lv[4];
    #pragma unroll
    for (int i = 0; i < 4; ++i) {
        hv[i] = f2bf(a[i]);
        lv[i] = f2bf(a[i] - bf2f(hv[i]));
    }
    size_t base = (size_t)n * HID + 4 * lane;
    *(short4*)&h1h[base] = make_short4(hv[0], hv[1], hv[2], hv[3]);
    *(short4*)&h1l[base] = make_short4(lv[0], lv[1], lv[2], lv[3]);
}

// ---------------- launch ----------------

extern "C" void kernel_launch(void* const* d_in, const int* in_sizes, int n_in,
                              void* d_out, int out_size, void* d_ws, size_t ws_size,
                              hipStream_t stream) {
    const float* x  = (const float*)d_in[0];
    const int*   ei = (const int*)d_in[1];
    const float* ew = (const float*)d_in[2];
    const float* W1 = (const float*)d_in[3];
    const float* b1 = (const float*)d_in[4];
    const float* W2 = (const float*)d_in[5];
    const float* b2 = (const float*)d_in[6];
    float* out = (float*)d_out;

    char* ws = (char*)d_ws;
    float* deg      = (float*)(ws);                         // 20000 f32  (becomes dinv)
    int*   counts   = (int*)(ws + 80000);                   // 20000 i32
    int*   cursor   = (int*)(ws + 160000);                  // 20000 i32
    int*   offs     = (int*)(ws + 240000);                  // 20001 i32 (pad to 80016)
    int*   csr_src  = (int*)(ws + 320016);                  // 320000 i32
    float* csr_norm = (float*)(ws + 1600016);               // 320000 f32
    float* xw       = (float*)(ws + 2880016);               // 20000x256 f32
    short* h1h      = (short*)(ws + 23360016);              // 20000x256 bf16
    short* h1l      = (short*)(ws + 33600016);              // 20000x256 bf16 (ends 43840016)

    hipMemsetAsync(d_ws, 0, 240000, stream);

    const int TB = 256;
    edge_count_deg<<<(N_EDGES + TB - 1) / TB, TB, 0, stream>>>(ei, ew, deg, counts);
    scan_counts<<<1, 1024, 0, stream>>>(counts, offs, deg, N_NODES);
    scatter_edges<<<(N_EDGES + TB - 1) / TB, TB, 0, stream>>>(ei, ew, deg, offs, cursor,
                                                              csr_src, csr_norm);

    const int GEMM_GRID = (N_NODES / 16) * 4;   // 1250 mt x 4 nt-groups = 5000 blocks
    // layer 1: K=168, 6 k-steps (octet-padded)
    mfma_gemm_f32a<<<GEMM_GRID, 256, 0, stream>>>(x, W1, xw, IN_F, 6);
    aggregate_split<<<N_NODES / 4, 256, 0, stream>>>((const float4*)xw, deg, offs, csr_src,
                                                     csr_norm, (const float4*)b1, h1h, h1l);
    // layer 2: K=256
    mfma_gemm_bf16a<<<GEMM_GRID, 256, 0, stream>>>(h1h, h1l, W2, xw);
    aggregate_out<<<N_NODES / 4, 256, 0, stream>>>((const float4*)xw, deg, offs, csr_src,
                                                   csr_norm, (const float4*)b2, (float4*)out);
}

// Round 7
// 300.511 us; speedup vs baseline: 2.1140x; 1.6875x over previous
//
#include <hip/hip_runtime.h>

#define N_NODES 20000
#define N_EDGES 320000
#define IN_F    168
#define HID     256
#define K1P     192   // IN_F zero-padded to multiple of 64

typedef __attribute__((ext_vector_type(8))) short bf16x8;
typedef __attribute__((ext_vector_type(4))) float f32x4;

// fp32 -> bf16 (round-to-nearest-even)
__device__ __forceinline__ short f2bf(float f) {
    union { float f; unsigned u; } v; v.f = f;
    unsigned r = v.u + 0x7FFFu + ((v.u >> 16) & 1u);
    return (short)(r >> 16);
}
__device__ __forceinline__ float bf2f(short s) {
    union { unsigned u; float f; } v; v.u = ((unsigned)(unsigned short)s) << 16;
    return v.f;
}

// ---------------- graph prep ----------------

__global__ void edge_count_deg(const int* __restrict__ ei, const float* __restrict__ ew,
                               float* __restrict__ deg, int* __restrict__ counts) {
    int e = blockIdx.x * blockDim.x + threadIdx.x;
    if (e >= N_EDGES) return;
    int d = ei[N_EDGES + e];
    atomicAdd(&deg[d], ew[e]);
    atomicAdd(&counts[d], 1);
}

// single-block scan: counts -> offs (exclusive, n+1); also deg -> rsqrt(deg+1)
__global__ void scan_counts(const int* __restrict__ counts, int* __restrict__ offs,
                            float* __restrict__ deg, int n) {
    int tid  = threadIdx.x;
    int lane = tid & 63;
    int wv   = tid >> 6;
    __shared__ int wsum[16];
    __shared__ int s_total;
    __shared__ int s_carry;
    if (tid == 0) s_carry = 0;
    __syncthreads();
    for (int base = 0; base < n; base += 1024) {
        int i = base + tid;
        if (i < n) deg[i] = rsqrtf(deg[i] + 1.0f);
        int v = (i < n) ? counts[i] : 0;
        int incl = v;
        #pragma unroll
        for (int d = 1; d < 64; d <<= 1) {
            int t = __shfl_up(incl, d);
            if (lane >= d) incl += t;
        }
        if (lane == 63) wsum[wv] = incl;
        __syncthreads();
        if (wv == 0) {
            int w = (lane < 16) ? wsum[lane] : 0;
            int winc = w;
            #pragma unroll
            for (int d = 1; d < 16; d <<= 1) {
                int t = __shfl_up(winc, d);
                if (lane >= d) winc += t;
            }
            if (lane < 16) wsum[lane] = winc - w;
            if (lane == 15) s_total = winc;
        }
        __syncthreads();
        int c = s_carry;
        if (i < n) offs[i] = c + wsum[wv] + incl - v;
        __syncthreads();
        if (tid == 0) s_carry = c + s_total;
        __syncthreads();
    }
    if (tid == 0) offs[n] = s_carry;
}

__global__ void scatter_edges(const int* __restrict__ ei, const float* __restrict__ ew,
                              const float* __restrict__ dinv, const int* __restrict__ offs,
                              int* __restrict__ cursor, int* __restrict__ csr_src,
                              float* __restrict__ csr_norm) {
    int e = blockIdx.x * blockDim.x + threadIdx.x;
    if (e >= N_EDGES) return;
    int s = ei[e];
    int d = ei[N_EDGES + e];
    int pos = offs[d] + atomicAdd(&cursor[d], 1);
    csr_src[pos]  = s;
    csr_norm[pos] = dinv[s] * ew[e] * dinv[d];
}

// ---------------- pre-split fp32 -> (hi, lo) bf16 ----------------

// x[20000x168] -> xh/xl[20000x192] (zero-padded)
__global__ void split_x(const float* __restrict__ x, short* __restrict__ xh,
                        short* __restrict__ xl) {
    int row = blockIdx.x;
    int k   = threadIdx.x;                     // 0..191
    float v = (k < IN_F) ? x[(size_t)row * IN_F + k] : 0.f;
    short h = f2bf(v);
    xh[(size_t)row * K1P + k] = h;
    xl[(size_t)row * K1P + k] = f2bf(v - bf2f(h));
}

// blocks 0..255: W1 row (168 -> 192 padded); blocks 256..511: W2 row (256)
__global__ void split_w(const float* __restrict__ W1, const float* __restrict__ W2,
                        short* __restrict__ w1h, short* __restrict__ w1l,
                        short* __restrict__ w2h, short* __restrict__ w2l) {
    int b = blockIdx.x;
    int k = threadIdx.x;                       // 0..255
    if (b < 256) {
        if (k >= K1P) return;
        float v = (k < IN_F) ? W1[(size_t)b * IN_F + k] : 0.f;
        short h = f2bf(v);
        w1h[(size_t)b * K1P + k] = h;
        w1l[(size_t)b * K1P + k] = f2bf(v - bf2f(h));
    } else {
        int r = b - 256;
        float v = W2[(size_t)r * HID + k];
        short h = f2bf(v);
        w2h[(size_t)r * HID + k] = h;
        w2l[(size_t)r * HID + k] = f2bf(v - bf2f(h));
    }
}

// ---------------- MFMA GEMM: C[M,256] = A[M,K] * W[256,K]^T ----------------
// Split-bf16 3-product: C ~= Ah*Wh + Ah*Wl + Al*Wh (fp32 MFMA accumulate).
// 64x64 block tile, 4 waves each 32x32 (2x2 of 16x16x32 MFMA), BK=64.
// Global->LDS staging coalesced (128B contiguous per 8 rows per wave);
// fragments via ds_read_b128 from LDS, row stride 72 shorts (144B, 16B-aligned,
// ~2-way banks = free). Register prefetch of next k-tile (R4 pattern).

#define LDS_STRIDE 72   // shorts per row (64 data + 8 pad)

__global__ __launch_bounds__(256) void gemm_split(const short* __restrict__ Ah,
                                                  const short* __restrict__ Al,
                                                  const short* __restrict__ Wh,
                                                  const short* __restrict__ Wl,
                                                  float* __restrict__ C,
                                                  int M, int Ks, int nsteps) {
    __shared__ short sAh[64 * LDS_STRIDE];
    __shared__ short sAl[64 * LDS_STRIDE];
    __shared__ short sWh[64 * LDS_STRIDE];
    __shared__ short sWl[64 * LDS_STRIDE];

    const int tid  = threadIdx.x;
    const int lane = tid & 63;
    const int wv   = tid >> 6;
    const int l16  = lane & 15;
    const int quad = lane >> 4;
    const int wm   = (wv & 1) * 32;
    const int wn   = (wv >> 1) * 32;
    const int bm   = blockIdx.x * 64;
    const int bn   = blockIdx.y * 64;

    // staging coords: thread -> (row, 16-short segment)
    const int srow = tid >> 2;
    const int sseg = (tid & 3) * 16;
    int arow = bm + srow; if (arow >= M) arow = M - 1;   // clamp: finite garbage, rows not stored
    const short* gAh = Ah + (size_t)arow * Ks;
    const short* gAl = Al + (size_t)arow * Ks;
    const short* gWh = Wh + (size_t)(bn + srow) * Ks;
    const short* gWl = Wl + (size_t)(bn + srow) * Ks;
    const int lds_off = srow * LDS_STRIDE + sseg;

    f32x4 acc00 = {0,0,0,0}, acc01 = {0,0,0,0}, acc10 = {0,0,0,0}, acc11 = {0,0,0,0};

    // prefetch k-step 0 (16 shorts = 2 int4 per array per thread)
    int4 pah0 = *(const int4*)(gAh + sseg), pah1 = *(const int4*)(gAh + sseg + 8);
    int4 pal0 = *(const int4*)(gAl + sseg), pal1 = *(const int4*)(gAl + sseg + 8);
    int4 pwh0 = *(const int4*)(gWh + sseg), pwh1 = *(const int4*)(gWh + sseg + 8);
    int4 pwl0 = *(const int4*)(gWl + sseg), pwl1 = *(const int4*)(gWl + sseg + 8);

    for (int ks = 0; ks < nsteps; ++ks) {
        *(int4*)&sAh[lds_off] = pah0; *(int4*)&sAh[lds_off + 8] = pah1;
        *(int4*)&sAl[lds_off] = pal0; *(int4*)&sAl[lds_off + 8] = pal1;
        *(int4*)&sWh[lds_off] = pwh0; *(int4*)&sWh[lds_off + 8] = pwh1;
        *(int4*)&sWl[lds_off] = pwl0; *(int4*)&sWl[lds_off + 8] = pwl1;
        __syncthreads();
        if (ks + 1 < nsteps) {                 // uniform branch; loads fly over compute
            int o = (ks + 1) * 64 + sseg;
            pah0 = *(const int4*)(gAh + o); pah1 = *(const int4*)(gAh + o + 8);
            pal0 = *(const int4*)(gAl + o); pal1 = *(const int4*)(gAl + o + 8);
            pwh0 = *(const int4*)(gWh + o); pwh1 = *(const int4*)(gWh + o + 8);
            pwl0 = *(const int4*)(gWl + o); pwl1 = *(const int4*)(gWl + o + 8);
        }
        #pragma unroll
        for (int o = 0; o < 2; ++o) {
            const int a0 = (wm + l16) * LDS_STRIDE + o * 32 + quad * 8;
            const int a1 = a0 + 16 * LDS_STRIDE;
            const int w0 = (wn + l16) * LDS_STRIDE + o * 32 + quad * 8;
            const int w1 = w0 + 16 * LDS_STRIDE;
            bf16x8 ah0 = *(const bf16x8*)&sAh[a0];
            bf16x8 ah1 = *(const bf16x8*)&sAh[a1];
            bf16x8 al0 = *(const bf16x8*)&sAl[a0];
            bf16x8 al1 = *(const bf16x8*)&sAl[a1];
            bf16x8 wh0 = *(const bf16x8*)&sWh[w0];
            bf16x8 wh1 = *(const bf16x8*)&sWh[w1];
            bf16x8 wl0 = *(const bf16x8*)&sWl[w0];
            bf16x8 wl1 = *(const bf16x8*)&sWl[w1];
            acc00 = __builtin_amdgcn_mfma_f32_16x16x32_bf16(ah0, wh0, acc00, 0, 0, 0);
            acc00 = __builtin_amdgcn_mfma_f32_16x16x32_bf16(ah0, wl0, acc00, 0, 0, 0);
            acc00 = __builtin_amdgcn_mfma_f32_16x16x32_bf16(al0, wh0, acc00, 0, 0, 0);
            acc01 = __builtin_amdgcn_mfma_f32_16x16x32_bf16(ah0, wh1, acc01, 0, 0, 0);
            acc01 = __builtin_amdgcn_mfma_f32_16x16x32_bf16(ah0, wl1, acc01, 0, 0, 0);
            acc01 = __builtin_amdgcn_mfma_f32_16x16x32_bf16(al0, wh1, acc01, 0, 0, 0);
            acc10 = __builtin_amdgcn_mfma_f32_16x16x32_bf16(ah1, wh0, acc10, 0, 0, 0);
            acc10 = __builtin_amdgcn_mfma_f32_16x16x32_bf16(ah1, wl0, acc10, 0, 0, 0);
            acc10 = __builtin_amdgcn_mfma_f32_16x16x32_bf16(al1, wh0, acc10, 0, 0, 0);
            acc11 = __builtin_amdgcn_mfma_f32_16x16x32_bf16(ah1, wh1, acc11, 0, 0, 0);
            acc11 = __builtin_amdgcn_mfma_f32_16x16x32_bf16(ah1, wl1, acc11, 0, 0, 0);
            acc11 = __builtin_amdgcn_mfma_f32_16x16x32_bf16(al1, wh1, acc11, 0, 0, 0);
        }
        __syncthreads();
    }

    // C/D layout: col = lane&15, row = quad*4 + reg
    const int colb = bn + wn + l16;
    const int rowb = bm + wm + quad * 4;
    #pragma unroll
    for (int r = 0; r < 4; ++r) {
        int row = rowb + r;
        if (row < M) {
            C[(size_t)row * HID + colb]          = acc00[r];
            C[(size_t)row * HID + colb + 16]     = acc01[r];
        }
        if (row + 16 < M) {
            C[(size_t)(row + 16) * HID + colb]      = acc10[r];
            C[(size_t)(row + 16) * HID + colb + 16] = acc11[r];
        }
    }
}

// ---------------- aggregation (+self-loop, +bias, ReLU) ----------------

__device__ __forceinline__ void agg_body(const float4* __restrict__ xw4,
                                         const float* __restrict__ dinv,
                                         const int* __restrict__ offs,
                                         const int* __restrict__ csr_src,
                                         const float* __restrict__ csr_norm,
                                         const float4* __restrict__ bias4,
                                         int n, int lane, float4& o) {
    float di = dinv[n];
    float sw = di * di;
    float4 v = xw4[(size_t)n * 64 + lane];
    float ax = sw * v.x, ay = sw * v.y, az = sw * v.z, aw = sw * v.w;

    int p0 = offs[n], p1 = offs[n + 1];
    int p = p0;
    for (; p + 4 <= p1; p += 4) {
        int   s0 = csr_src[p],     s1 = csr_src[p + 1];
        int   s2 = csr_src[p + 2], s3 = csr_src[p + 3];
        float w0 = csr_norm[p],     w1 = csr_norm[p + 1];
        float w2 = csr_norm[p + 2], w3 = csr_norm[p + 3];
        float4 r0 = xw4[(size_t)s0 * 64 + lane];
        float4 r1 = xw4[(size_t)s1 * 64 + lane];
        float4 r2 = xw4[(size_t)s2 * 64 + lane];
        float4 r3 = xw4[(size_t)s3 * 64 + lane];
        ax += w0 * r0.x + w1 * r1.x + w2 * r2.x + w3 * r3.x;
        ay += w0 * r0.y + w1 * r1.y + w2 * r2.y + w3 * r3.y;
        az += w0 * r0.z + w1 * r1.z + w2 * r2.z + w3 * r3.z;
        aw += w0 * r0.w + w1 * r1.w + w2 * r2.w + w3 * r3.w;
    }
    for (; p < p1; ++p) {
        int   s0 = csr_src[p];
        float w0 = csr_norm[p];
        float4 r0 = xw4[(size_t)s0 * 64 + lane];
        ax += w0 * r0.x; ay += w0 * r0.y; az += w0 * r0.z; aw += w0 * r0.w;
    }

    float4 b = bias4[lane];
    ax += b.x; ay += b.y; az += b.z; aw += b.w;
    o.x = ax > 0.f ? ax : 0.f;
    o.y = ay > 0.f ? ay : 0.f;
    o.z = az > 0.f ? az : 0.f;
    o.w = aw > 0.f ? aw : 0.f;
}

__global__ __launch_bounds__(256) void aggregate_out(const float4* __restrict__ xw4,
                                                     const float* __restrict__ dinv,
                                                     const int* __restrict__ offs,
                                                     const int* __restrict__ csr_src,
                                                     const float* __restrict__ csr_norm,
                                                     const float4* __restrict__ bias4,
                                                     float4* __restrict__ out4) {
    int wave = threadIdx.x >> 6;
    int lane = threadIdx.x & 63;
    int n = blockIdx.x * 4 + wave;
    float4 o;
    agg_body(xw4, dinv, offs, csr_src, csr_norm, bias4, n, lane, o);
    out4[(size_t)n * 64 + lane] = o;
}

__global__ __launch_bounds__(256) void aggregate_split(const float4* __restrict__ xw4,
                                                       const float* __restrict__ dinv,
                                                       const int* __restrict__ offs,
                                                       const int* __restrict__ csr_src,
                                                       const float* __restrict__ csr_norm,
                                                       const float4* __restrict__ bias4,
                                                       short* __restrict__ h1h,
                                                       short* __restrict__ h1l) {
    int wave = threadIdx.x >> 6;
    int lane = threadIdx.x & 63;
    int n = blockIdx.x * 4 + wave;
    float4 o;
    agg_body(xw4, dinv, offs, csr_src, csr_norm, bias4, n, lane, o);
    float a[4] = {o.x, o.y, o.z, o.w};
    short hv[4], lv[4];
    #pragma unroll
    for (int i = 0; i < 4; ++i) {
        hv[i] = f2bf(a[i]);
        lv[i] = f2bf(a[i] - bf2f(hv[i]));
    }
    size_t base = (size_t)n * HID + 4 * lane;
    *(short4*)&h1h[base] = make_short4(hv[0], hv[1], hv[2], hv[3]);
    *(short4*)&h1l[base] = make_short4(lv[0], lv[1], lv[2], lv[3]);
}

// ---------------- launch ----------------

extern "C" void kernel_launch(void* const* d_in, const int* in_sizes, int n_in,
                              void* d_out, int out_size, void* d_ws, size_t ws_size,
                              hipStream_t stream) {
    const float* x  = (const float*)d_in[0];
    const int*   ei = (const int*)d_in[1];
    const float* ew = (const float*)d_in[2];
    const float* W1 = (const float*)d_in[3];
    const float* b1 = (const float*)d_in[4];
    const float* W2 = (const float*)d_in[5];
    const float* b2 = (const float*)d_in[6];
    float* out = (float*)d_out;

    char* ws = (char*)d_ws;
    float* deg      = (float*)(ws);                 // 20000 f32 (becomes dinv)
    int*   counts   = (int*)(ws + 80000);           // 20000 i32
    int*   cursor   = (int*)(ws + 160000);          // 20000 i32
    int*   offs     = (int*)(ws + 240000);          // 20001 i32
    int*   csr_src  = (int*)(ws + 320016);          // 320000 i32
    float* csr_norm = (float*)(ws + 1600016);       // 320000 f32
    float* xw       = (float*)(ws + 2880016);       // 20000x256 f32
    // shared region S (20.48 MB): phase 1 = xh/xl (20000x192 bf16 each, 15.36 MB);
    // phase 2 = h1h/h1l (20000x256 bf16 each). Safe: xh/xl dead after gemm L1,
    // aggregate_split (which writes h1h/h1l) runs after gemm L1 completes.
    char*  S        = ws + 23360016;
    short* xh       = (short*)(S);
    short* xl       = (short*)(S + 7680000);
    short* h1h      = (short*)(S);
    short* h1l      = (short*)(S + 10240000);
    short* w1h      = (short*)(ws + 43840016);      // 256x192 bf16
    short* w1l      = (short*)(ws + 43938320);
    short* w2h      = (short*)(ws + 44036624);      // 256x256 bf16
    short* w2l      = (short*)(ws + 44167696);      // ends 44298768

    hipMemsetAsync(d_ws, 0, 240000, stream);

    const int TB = 256;
    edge_count_deg<<<(N_EDGES + TB - 1) / TB, TB, 0, stream>>>(ei, ew, deg, counts);
    scan_counts<<<1, 1024, 0, stream>>>(counts, offs, deg, N_NODES);
    scatter_edges<<<(N_EDGES + TB - 1) / TB, TB, 0, stream>>>(ei, ew, deg, offs, cursor,
                                                              csr_src, csr_norm);
    split_x<<<N_NODES, K1P, 0, stream>>>(x, xh, xl);
    split_w<<<512, 256, 0, stream>>>(W1, W2, w1h, w1l, w2h, w2l);

    dim3 gg((N_NODES + 63) / 64, 4);
    // layer 1: K padded 192 -> 3 k-steps of 64
    gemm_split<<<gg, 256, 0, stream>>>(xh, xl, w1h, w1l, xw, N_NODES, K1P, 3);
    aggregate_split<<<N_NODES / 4, 256, 0, stream>>>((const float4*)xw, deg, offs, csr_src,
                                                     csr_norm, (const float4*)b1, h1h, h1l);
    // layer 2: K=256 -> 4 k-steps
    gemm_split<<<gg, 256, 0, stream>>>(h1h, h1l, w2h, w2l, xw, N_NODES, HID, 4);
    aggregate_out<<<N_NODES / 4, 256, 0, stream>>>((const float4*)xw, deg, offs, csr_src,
                                                   csr_norm, (const float4*)b2, (float4*)out);
}

// Round 8
// 236.202 us; speedup vs baseline: 2.6896x; 1.2723x over previous
//
#include <hip/hip_runtime.h>

#define N_NODES 20000
#define N_EDGES 320000
#define IN_F    168
#define HID     256
#define K1P     192   // IN_F zero-padded to multiple of 64
#define NF4     42    // IN_F / 4

typedef __attribute__((ext_vector_type(8))) short bf16x8;
typedef __attribute__((ext_vector_type(4))) float f32x4;

__device__ __forceinline__ short f2bf(float f) {
    union { float f; unsigned u; } v; v.f = f;
    unsigned r = v.u + 0x7FFFu + ((v.u >> 16) & 1u);
    return (short)(r >> 16);
}
__device__ __forceinline__ float bf2f(short s) {
    union { unsigned u; float f; } v; v.u = ((unsigned)(unsigned short)s) << 16;
    return v.f;
}

// ---------------- graph prep ----------------

__global__ void edge_count_deg(const int* __restrict__ ei, const float* __restrict__ ew,
                               float* __restrict__ deg, int* __restrict__ counts) {
    int e = blockIdx.x * blockDim.x + threadIdx.x;
    if (e >= N_EDGES) return;
    int d = ei[N_EDGES + e];
    atomicAdd(&deg[d], ew[e]);
    atomicAdd(&counts[d], 1);
}

// two-kernel parallel scan: part (block-local exclusive + block totals, dinv fold)
__global__ __launch_bounds__(1024) void scan_part(const int* __restrict__ counts,
                                                  int* __restrict__ offs,
                                                  int* __restrict__ bsum,
                                                  float* __restrict__ deg, int n) {
    int tid  = threadIdx.x;
    int lane = tid & 63;
    int wv   = tid >> 6;
    int i = blockIdx.x * 1024 + tid;
    if (i < n) deg[i] = rsqrtf(deg[i] + 1.0f);     // self-loop weight 1.0
    __shared__ int wsum[16];
    int v = (i < n) ? counts[i] : 0;
    int incl = v;
    #pragma unroll
    for (int d = 1; d < 64; d <<= 1) {
        int t = __shfl_up(incl, d);
        if (lane >= d) incl += t;
    }
    if (lane == 63) wsum[wv] = incl;
    __syncthreads();
    if (wv == 0) {
        int w = (lane < 16) ? wsum[lane] : 0;
        int winc = w;
        #pragma unroll
        for (int d = 1; d < 16; d <<= 1) {
            int t = __shfl_up(winc, d);
            if (lane >= d) winc += t;
        }
        if (lane < 16) wsum[lane] = winc - w;      // exclusive wave offsets
    }
    __syncthreads();
    if (i < n) offs[i] = wsum[wv] + incl - v;      // block-local exclusive
    if (tid == 1023) bsum[blockIdx.x] = wsum[15] + incl;
}

__global__ __launch_bounds__(1024) void scan_add(const int* __restrict__ bsum,
                                                 int* __restrict__ offs, int n) {
    int i = blockIdx.x * 1024 + threadIdx.x;
    int add = 0;
    for (int b = 0; b < (int)blockIdx.x; ++b) add += bsum[b];
    if (i < n) offs[i] += add;
    if (i == n) offs[n] = add + bsum[blockIdx.x];
}

__global__ void scatter_edges(const int* __restrict__ ei, const float* __restrict__ ew,
                              const float* __restrict__ dinv, const int* __restrict__ offs,
                              int* __restrict__ cursor, int* __restrict__ csr_src,
                              float* __restrict__ csr_norm) {
    int e = blockIdx.x * blockDim.x + threadIdx.x;
    if (e >= N_EDGES) return;
    int s = ei[e];
    int d = ei[N_EDGES + e];
    int pos = offs[d] + atomicAdd(&cursor[d], 1);
    csr_src[pos]  = s;
    csr_norm[pos] = dinv[s] * ew[e] * dinv[d];
}

// ---------------- weight split ----------------
// blocks 0..255: W1 row (168 -> 192 padded); blocks 256..511: W2 row (256)
__global__ void split_w(const float* __restrict__ W1, const float* __restrict__ W2,
                        short* __restrict__ w1h, short* __restrict__ w1l,
                        short* __restrict__ w2h, short* __restrict__ w2l) {
    int b = blockIdx.x;
    int k = threadIdx.x;
    if (b < 256) {
        if (k >= K1P) return;
        float v = (k < IN_F) ? W1[(size_t)b * IN_F + k] : 0.f;
        short h = f2bf(v);
        w1h[(size_t)b * K1P + k] = h;
        w1l[(size_t)b * K1P + k] = f2bf(v - bf2f(h));
    } else {
        int r = b - 256;
        float v = W2[(size_t)r * HID + k];
        short h = f2bf(v);
        w2h[(size_t)r * HID + k] = h;
        w2l[(size_t)r * HID + k] = f2bf(v - bf2f(h));
    }
}

// ---------------- gathers (Agg BEFORE GEMM; emit split-bf16 A operand) ----------

// layer 1: agg_x[n] = dinv[n]^2 x[n] + sum norm*x[src]; x fp32 [20000x168].
// wave per node; lanes 0..41 own one float4 (4 features); emit 192-padded split.
__global__ __launch_bounds__(256) void agg_x_split(const float* __restrict__ x,
                                                   const float* __restrict__ dinv,
                                                   const int* __restrict__ offs,
                                                   const int* __restrict__ csr_src,
                                                   const float* __restrict__ csr_norm,
                                                   short* __restrict__ axh,
                                                   short* __restrict__ axl) {
    int wave = threadIdx.x >> 6;
    int lane = threadIdx.x & 63;
    int n = blockIdx.x * 4 + wave;
    bool act = lane < NF4;
    float di = dinv[n];
    float sw = di * di;
    float ax = 0.f, ay = 0.f, az = 0.f, aw = 0.f;
    if (act) {
        float4 v = *(const float4*)(x + (size_t)n * IN_F + lane * 4);
        ax = sw * v.x; ay = sw * v.y; az = sw * v.z; aw = sw * v.w;
    }
    int p0 = offs[n], p1 = offs[n + 1];
    int p = p0;
    for (; p + 4 <= p1; p += 4) {
        int   s0 = csr_src[p],     s1 = csr_src[p + 1];
        int   s2 = csr_src[p + 2], s3 = csr_src[p + 3];
        float w0 = csr_norm[p],     w1 = csr_norm[p + 1];
        float w2 = csr_norm[p + 2], w3 = csr_norm[p + 3];
        if (act) {
            float4 r0 = *(const float4*)(x + (size_t)s0 * IN_F + lane * 4);
            float4 r1 = *(const float4*)(x + (size_t)s1 * IN_F + lane * 4);
            float4 r2 = *(const float4*)(x + (size_t)s2 * IN_F + lane * 4);
            float4 r3 = *(const float4*)(x + (size_t)s3 * IN_F + lane * 4);
            ax += w0 * r0.x + w1 * r1.x + w2 * r2.x + w3 * r3.x;
            ay += w0 * r0.y + w1 * r1.y + w2 * r2.y + w3 * r3.y;
            az += w0 * r0.z + w1 * r1.z + w2 * r2.z + w3 * r3.z;
            aw += w0 * r0.w + w1 * r1.w + w2 * r2.w + w3 * r3.w;
        }
    }
    for (; p < p1; ++p) {
        int   s0 = csr_src[p];
        float w0 = csr_norm[p];
        if (act) {
            float4 r0 = *(const float4*)(x + (size_t)s0 * IN_F + lane * 4);
            ax += w0 * r0.x; ay += w0 * r0.y; az += w0 * r0.z; aw += w0 * r0.w;
        }
    }
    size_t base = (size_t)n * K1P + lane * 4;
    if (act) {
        float a[4] = {ax, ay, az, aw};
        short hv[4], lv[4];
        #pragma unroll
        for (int i = 0; i < 4; ++i) {
            hv[i] = f2bf(a[i]);
            lv[i] = f2bf(a[i] - bf2f(hv[i]));
        }
        *(short4*)&axh[base] = make_short4(hv[0], hv[1], hv[2], hv[3]);
        *(short4*)&axl[base] = make_short4(lv[0], lv[1], lv[2], lv[3]);
    } else if (lane < 48) {                     // zero pad cols 168..191
        short4 z = make_short4(0, 0, 0, 0);
        *(short4*)&axh[base] = z;
        *(short4*)&axl[base] = z;
    }
}

// layer 2: agg_h from bf16-hi h1 [20000x256]; 512B rows, one short4 per lane.
__global__ __launch_bounds__(256) void agg_h_split(const short* __restrict__ h1h,
                                                   const float* __restrict__ dinv,
                                                   const int* __restrict__ offs,
                                                   const int* __restrict__ csr_src,
                                                   const float* __restrict__ csr_norm,
                                                   short* __restrict__ ahh,
                                                   short* __restrict__ ahl) {
    int wave = threadIdx.x >> 6;
    int lane = threadIdx.x & 63;
    int n = blockIdx.x * 4 + wave;
    float di = dinv[n];
    float sw = di * di;
    short4 sv = *(const short4*)(h1h + (size_t)n * HID + lane * 4);
    float ax = sw * bf2f(sv.x), ay = sw * bf2f(sv.y);
    float az = sw * bf2f(sv.z), aw = sw * bf2f(sv.w);
    int p0 = offs[n], p1 = offs[n + 1];
    int p = p0;
    for (; p + 4 <= p1; p += 4) {
        int   s0 = csr_src[p],     s1 = csr_src[p + 1];
        int   s2 = csr_src[p + 2], s3 = csr_src[p + 3];
        float w0 = csr_norm[p],     w1 = csr_norm[p + 1];
        float w2 = csr_norm[p + 2], w3 = csr_norm[p + 3];
        short4 r0 = *(const short4*)(h1h + (size_t)s0 * HID + lane * 4);
        short4 r1 = *(const short4*)(h1h + (size_t)s1 * HID + lane * 4);
        short4 r2 = *(const short4*)(h1h + (size_t)s2 * HID + lane * 4);
        short4 r3 = *(const short4*)(h1h + (size_t)s3 * HID + lane * 4);
        ax += w0 * bf2f(r0.x) + w1 * bf2f(r1.x) + w2 * bf2f(r2.x) + w3 * bf2f(r3.x);
        ay += w0 * bf2f(r0.y) + w1 * bf2f(r1.y) + w2 * bf2f(r2.y) + w3 * bf2f(r3.y);
        az += w0 * bf2f(r0.z) + w1 * bf2f(r1.z) + w2 * bf2f(r2.z) + w3 * bf2f(r3.z);
        aw += w0 * bf2f(r0.w) + w1 * bf2f(r1.w) + w2 * bf2f(r2.w) + w3 * bf2f(r3.w);
    }
    for (; p < p1; ++p) {
        int   s0 = csr_src[p];
        float w0 = csr_norm[p];
        short4 r0 = *(const short4*)(h1h + (size_t)s0 * HID + lane * 4);
        ax += w0 * bf2f(r0.x); ay += w0 * bf2f(r0.y);
        az += w0 * bf2f(r0.z); aw += w0 * bf2f(r0.w);
    }
    float a[4] = {ax, ay, az, aw};
    short hv[4], lv[4];
    #pragma unroll
    for (int i = 0; i < 4; ++i) {
        hv[i] = f2bf(a[i]);
        lv[i] = f2bf(a[i] - bf2f(hv[i]));
    }
    size_t base = (size_t)n * HID + lane * 4;
    *(short4*)&ahh[base] = make_short4(hv[0], hv[1], hv[2], hv[3]);
    *(short4*)&ahl[base] = make_short4(lv[0], lv[1], lv[2], lv[3]);
}

// ---------------- MFMA GEMM with fused bias+ReLU epilogue ----------------
// C[M,256] = relu(A[M,K] * W[256,K]^T + bias). Split-bf16 3-product.
// 64x64 tile, 4 waves each 32x32 (2x2 MFMA 16x16x32), BK=64, LDS-staged,
// register prefetch. mode 0: store bf16-hi to Cbf; mode 1: store fp32 to Cf.

#define LDS_STRIDE 72

__global__ __launch_bounds__(256) void gemm_split(const short* __restrict__ Ah,
                                                  const short* __restrict__ Al,
                                                  const short* __restrict__ Wh,
                                                  const short* __restrict__ Wl,
                                                  const float* __restrict__ bias,
                                                  float* __restrict__ Cf,
                                                  short* __restrict__ Cbf,
                                                  int M, int Ks, int nsteps, int mode) {
    __shared__ short sAh[64 * LDS_STRIDE];
    __shared__ short sAl[64 * LDS_STRIDE];
    __shared__ short sWh[64 * LDS_STRIDE];
    __shared__ short sWl[64 * LDS_STRIDE];

    const int tid  = threadIdx.x;
    const int lane = tid & 63;
    const int wv   = tid >> 6;
    const int l16  = lane & 15;
    const int quad = lane >> 4;
    const int wm   = (wv & 1) * 32;
    const int wn   = (wv >> 1) * 32;
    const int bm   = blockIdx.x * 64;
    const int bn   = blockIdx.y * 64;

    const int srow = tid >> 2;
    const int sseg = (tid & 3) * 16;
    int arow = bm + srow; if (arow >= M) arow = M - 1;
    const short* gAh = Ah + (size_t)arow * Ks;
    const short* gAl = Al + (size_t)arow * Ks;
    const short* gWh = Wh + (size_t)(bn + srow) * Ks;
    const short* gWl = Wl + (size_t)(bn + srow) * Ks;
    const int lds_off = srow * LDS_STRIDE + sseg;

    f32x4 acc00 = {0,0,0,0}, acc01 = {0,0,0,0}, acc10 = {0,0,0,0}, acc11 = {0,0,0,0};

    int4 pah0 = *(const int4*)(gAh + sseg), pah1 = *(const int4*)(gAh + sseg + 8);
    int4 pal0 = *(const int4*)(gAl + sseg), pal1 = *(const int4*)(gAl + sseg + 8);
    int4 pwh0 = *(const int4*)(gWh + sseg), pwh1 = *(const int4*)(gWh + sseg + 8);
    int4 pwl0 = *(const int4*)(gWl + sseg), pwl1 = *(const int4*)(gWl + sseg + 8);

    for (int ks = 0; ks < nsteps; ++ks) {
        *(int4*)&sAh[lds_off] = pah0; *(int4*)&sAh[lds_off + 8] = pah1;
        *(int4*)&sAl[lds_off] = pal0; *(int4*)&sAl[lds_off + 8] = pal1;
        *(int4*)&sWh[lds_off] = pwh0; *(int4*)&sWh[lds_off + 8] = pwh1;
        *(int4*)&sWl[lds_off] = pwl0; *(int4*)&sWl[lds_off + 8] = pwl1;
        __syncthreads();
        if (ks + 1 < nsteps) {
            int o = (ks + 1) * 64 + sseg;
            pah0 = *(const int4*)(gAh + o); pah1 = *(const int4*)(gAh + o + 8);
            pal0 = *(const int4*)(gAl + o); pal1 = *(const int4*)(gAl + o + 8);
            pwh0 = *(const int4*)(gWh + o); pwh1 = *(const int4*)(gWh + o + 8);
            pwl0 = *(const int4*)(gWl + o); pwl1 = *(const int4*)(gWl + o + 8);
        }
        #pragma unroll
        for (int o = 0; o < 2; ++o) {
            const int a0 = (wm + l16) * LDS_STRIDE + o * 32 + quad * 8;
            const int a1 = a0 + 16 * LDS_STRIDE;
            const int w0 = (wn + l16) * LDS_STRIDE + o * 32 + quad * 8;
            const int w1 = w0 + 16 * LDS_STRIDE;
            bf16x8 ah0 = *(const bf16x8*)&sAh[a0];
            bf16x8 ah1 = *(const bf16x8*)&sAh[a1];
            bf16x8 al0 = *(const bf16x8*)&sAl[a0];
            bf16x8 al1 = *(const bf16x8*)&sAl[a1];
            bf16x8 wh0 = *(const bf16x8*)&sWh[w0];
            bf16x8 wh1 = *(const bf16x8*)&sWh[w1];
            bf16x8 wl0 = *(const bf16x8*)&sWl[w0];
            bf16x8 wl1 = *(const bf16x8*)&sWl[w1];
            acc00 = __builtin_amdgcn_mfma_f32_16x16x32_bf16(ah0, wh0, acc00, 0, 0, 0);
            acc00 = __builtin_amdgcn_mfma_f32_16x16x32_bf16(ah0, wl0, acc00, 0, 0, 0);
            acc00 = __builtin_amdgcn_mfma_f32_16x16x32_bf16(al0, wh0, acc00, 0, 0, 0);
            acc01 = __builtin_amdgcn_mfma_f32_16x16x32_bf16(ah0, wh1, acc01, 0, 0, 0);
            acc01 = __builtin_amdgcn_mfma_f32_16x16x32_bf16(ah0, wl1, acc01, 0, 0, 0);
            acc01 = __builtin_amdgcn_mfma_f32_16x16x32_bf16(al0, wh1, acc01, 0, 0, 0);
            acc10 = __builtin_amdgcn_mfma_f32_16x16x32_bf16(ah1, wh0, acc10, 0, 0, 0);
            acc10 = __builtin_amdgcn_mfma_f32_16x16x32_bf16(ah1, wl0, acc10, 0, 0, 0);
            acc10 = __builtin_amdgcn_mfma_f32_16x16x32_bf16(al1, wh0, acc10, 0, 0, 0);
            acc11 = __builtin_amdgcn_mfma_f32_16x16x32_bf16(ah1, wh1, acc11, 0, 0, 0);
            acc11 = __builtin_amdgcn_mfma_f32_16x16x32_bf16(ah1, wl1, acc11, 0, 0, 0);
            acc11 = __builtin_amdgcn_mfma_f32_16x16x32_bf16(al1, wh1, acc11, 0, 0, 0);
        }
        __syncthreads();
    }

    const int colb = bn + wn + l16;
    const int rowb = bm + wm + quad * 4;
    const float b0 = bias[colb];
    const float b1 = bias[colb + 16];
    #pragma unroll
    for (int r = 0; r < 4; ++r) {
        int row = rowb + r;
        if (row < M) {
            float v0 = acc00[r] + b0; v0 = v0 > 0.f ? v0 : 0.f;
            float v1 = acc01[r] + b1; v1 = v1 > 0.f ? v1 : 0.f;
            if (mode == 0) {
                Cbf[(size_t)row * HID + colb]      = f2bf(v0);
                Cbf[(size_t)row * HID + colb + 16] = f2bf(v1);
            } else {
                Cf[(size_t)row * HID + colb]      = v0;
                Cf[(size_t)row * HID + colb + 16] = v1;
            }
        }
        int row2 = row + 16;
        if (row2 < M) {
            float v0 = acc10[r] + b0; v0 = v0 > 0.f ? v0 : 0.f;
            float v1 = acc11[r] + b1; v1 = v1 > 0.f ? v1 : 0.f;
            if (mode == 0) {
                Cbf[(size_t)row2 * HID + colb]      = f2bf(v0);
                Cbf[(size_t)row2 * HID + colb + 16] = f2bf(v1);
            } else {
                Cf[(size_t)row2 * HID + colb]      = v0;
                Cf[(size_t)row2 * HID + colb + 16] = v1;
            }
        }
    }
}

// ---------------- launch ----------------

extern "C" void kernel_launch(void* const* d_in, const int* in_sizes, int n_in,
                              void* d_out, int out_size, void* d_ws, size_t ws_size,
                              hipStream_t stream) {
    const float* x  = (const float*)d_in[0];
    const int*   ei = (const int*)d_in[1];
    const float* ew = (const float*)d_in[2];
    const float* W1 = (const float*)d_in[3];
    const float* b1 = (const float*)d_in[4];
    const float* W2 = (const float*)d_in[5];
    const float* b2 = (const float*)d_in[6];
    float* out = (float*)d_out;

    char* ws = (char*)d_ws;
    float* deg      = (float*)(ws);                 // 20000 f32 (becomes dinv)
    int*   counts   = (int*)(ws + 80000);           // 20000 i32
    int*   cursor   = (int*)(ws + 160000);          // 20000 i32
    int*   offs     = (int*)(ws + 240000);          // 20001 i32
    int*   bsum     = (int*)(ws + 320016);          // 20 i32 (pad to 320144)
    int*   csr_src  = (int*)(ws + 320144);          // 320000 i32 -> 1600144
    float* csr_norm = (float*)(ws + 1600144);       // 320000 f32 -> 2880144
    // region A: agg_x split (2 x 20000x192 bf16 = 15.36MB), dead after gemm1;
    // reused for agg_h split (2 x 20000x256 bf16 = 20.48MB)
    short* axh      = (short*)(ws + 2880144);       // -> 10560144
    short* axl      = (short*)(ws + 10560144);      // -> 18240144
    short* ahh      = (short*)(ws + 2880144);       // -> 13120144
    short* ahl      = (short*)(ws + 13120144);      // -> 23360144
    short* h1h      = (short*)(ws + 23360144);      // 20000x256 bf16 -> 33600144
    short* w1h      = (short*)(ws + 33600144);      // 256x192 -> 33698448
    short* w1l      = (short*)(ws + 33698448);      // -> 33796752
    short* w2h      = (short*)(ws + 33796752);      // 256x256 -> 33927824
    short* w2l      = (short*)(ws + 33927824);      // -> 34058896

    hipMemsetAsync(d_ws, 0, 240000, stream);        // deg, counts, cursor

    const int TB = 256;
    edge_count_deg<<<(N_EDGES + TB - 1) / TB, TB, 0, stream>>>(ei, ew, deg, counts);
    scan_part<<<20, 1024, 0, stream>>>(counts, offs, bsum, deg, N_NODES);
    scan_add<<<20, 1024, 0, stream>>>(bsum, offs, N_NODES);
    scatter_edges<<<(N_EDGES + TB - 1) / TB, TB, 0, stream>>>(ei, ew, deg, offs, cursor,
                                                              csr_src, csr_norm);
    split_w<<<512, 256, 0, stream>>>(W1, W2, w1h, w1l, w2h, w2l);

    dim3 gg((N_NODES + 63) / 64, 4);
    // layer 1: Agg(x) -> split; GEMM(+b1, ReLU) -> h1 bf16-hi
    agg_x_split<<<N_NODES / 4, 256, 0, stream>>>(x, deg, offs, csr_src, csr_norm, axh, axl);
    gemm_split<<<gg, 256, 0, stream>>>(axh, axl, w1h, w1l, b1, nullptr, h1h,
                                       N_NODES, K1P, 3, 0);
    // layer 2: Agg(h1) -> split; GEMM(+b2, ReLU) -> out fp32
    agg_h_split<<<N_NODES / 4, 256, 0, stream>>>(h1h, deg, offs, csr_src, csr_norm, ahh, ahl);
    gemm_split<<<gg, 256, 0, stream>>>(ahh, ahl, w2h, w2l, b2, out, nullptr,
                                       N_NODES, HID, 4, 1);
}

// Round 9
// 230.560 us; speedup vs baseline: 2.7554x; 1.0245x over previous
//
#include <hip/hip_runtime.h>

#define N_NODES 20000
#define N_EDGES 320000
#define IN_F    168
#define HID     256
#define K1P     192   // IN_F zero-padded to multiple of 64
#define NF4     42    // IN_F / 4

typedef __attribute__((ext_vector_type(8))) short bf16x8;
typedef __attribute__((ext_vector_type(4))) float f32x4;

__device__ __forceinline__ short f2bf(float f) {
    union { float f; unsigned u; } v; v.f = f;
    unsigned r = v.u + 0x7FFFu + ((v.u >> 16) & 1u);
    return (short)(r >> 16);
}
__device__ __forceinline__ float bf2f(short s) {
    union { unsigned u; float f; } v; v.u = ((unsigned)(unsigned short)s) << 16;
    return v.f;
}

// ---------------- graph prep ----------------

__global__ void edge_count_deg(const int* __restrict__ ei, const float* __restrict__ ew,
                               float* __restrict__ deg, int* __restrict__ counts) {
    int e = blockIdx.x * blockDim.x + threadIdx.x;
    if (e >= N_EDGES) return;
    int d = ei[N_EDGES + e];
    atomicAdd(&deg[d], ew[e]);
    atomicAdd(&counts[d], 1);
}

// two-kernel parallel scan: part (block-local exclusive + block totals, dinv fold)
__global__ __launch_bounds__(1024) void scan_part(const int* __restrict__ counts,
                                                  int* __restrict__ offs,
                                                  int* __restrict__ bsum,
                                                  float* __restrict__ deg, int n) {
    int tid  = threadIdx.x;
    int lane = tid & 63;
    int wv   = tid >> 6;
    int i = blockIdx.x * 1024 + tid;
    if (i < n) deg[i] = rsqrtf(deg[i] + 1.0f);     // self-loop weight 1.0
    __shared__ int wsum[16];
    int v = (i < n) ? counts[i] : 0;
    int incl = v;
    #pragma unroll
    for (int d = 1; d < 64; d <<= 1) {
        int t = __shfl_up(incl, d);
        if (lane >= d) incl += t;
    }
    if (lane == 63) wsum[wv] = incl;
    __syncthreads();
    if (wv == 0) {
        int w = (lane < 16) ? wsum[lane] : 0;
        int winc = w;
        #pragma unroll
        for (int d = 1; d < 16; d <<= 1) {
            int t = __shfl_up(winc, d);
            if (lane >= d) winc += t;
        }
        if (lane < 16) wsum[lane] = winc - w;      // exclusive wave offsets
    }
    __syncthreads();
    if (i < n) offs[i] = wsum[wv] + incl - v;      // block-local exclusive
    if (tid == 1023) bsum[blockIdx.x] = wsum[15] + incl;
}

__global__ __launch_bounds__(1024) void scan_add(const int* __restrict__ bsum,
                                                 int* __restrict__ offs, int n) {
    int i = blockIdx.x * 1024 + threadIdx.x;
    int add = 0;
    for (int b = 0; b < (int)blockIdx.x; ++b) add += bsum[b];
    if (i < n) offs[i] += add;
    if (i == n) offs[n] = add + bsum[blockIdx.x];
}

__global__ void scatter_edges(const int* __restrict__ ei, const float* __restrict__ ew,
                              const float* __restrict__ dinv, const int* __restrict__ offs,
                              int* __restrict__ cursor, int* __restrict__ csr_src,
                              float* __restrict__ csr_norm) {
    int e = blockIdx.x * blockDim.x + threadIdx.x;
    if (e >= N_EDGES) return;
    int s = ei[e];
    int d = ei[N_EDGES + e];
    int pos = offs[d] + atomicAdd(&cursor[d], 1);
    csr_src[pos]  = s;
    csr_norm[pos] = dinv[s] * ew[e] * dinv[d];
}

// ---------------- conversions / weight split ----------------

// x fp32 [20000*168] -> xb bf16 (same layout, 336B rows)
__global__ void conv_x(const float* __restrict__ x, short* __restrict__ xb) {
    int i = blockIdx.x * blockDim.x + threadIdx.x;          // float4 index
    const int n4 = (N_NODES * IN_F) / 4;                    // 840000
    if (i >= n4) return;
    float4 v = *(const float4*)(x + (size_t)i * 4);
    *(short4*)(xb + (size_t)i * 4) =
        make_short4(f2bf(v.x), f2bf(v.y), f2bf(v.z), f2bf(v.w));
}

// blocks 0..255: W1 row (168 -> 192 padded); blocks 256..511: W2 row (256)
__global__ void split_w(const float* __restrict__ W1, const float* __restrict__ W2,
                        short* __restrict__ w1h, short* __restrict__ w1l,
                        short* __restrict__ w2h, short* __restrict__ w2l) {
    int b = blockIdx.x;
    int k = threadIdx.x;
    if (b < 256) {
        if (k >= K1P) return;
        float v = (k < IN_F) ? W1[(size_t)b * IN_F + k] : 0.f;
        short h = f2bf(v);
        w1h[(size_t)b * K1P + k] = h;
        w1l[(size_t)b * K1P + k] = f2bf(v - bf2f(h));
    } else {
        int r = b - 256;
        float v = W2[(size_t)r * HID + k];
        short h = f2bf(v);
        w2h[(size_t)r * HID + k] = h;
        w2l[(size_t)r * HID + k] = f2bf(v - bf2f(h));
    }
}

// ---------------- gathers (Agg BEFORE GEMM; emit split-bf16 A operand) ----------

// layer 1: agg from bf16 x rows (336B); wave per node, lanes 0..41 own short4.
// 8-deep ILP edge loop (8 outstanding row loads).
__global__ __launch_bounds__(256) void agg_x_split(const short* __restrict__ xb,
                                                   const float* __restrict__ dinv,
                                                   const int* __restrict__ offs,
                                                   const int* __restrict__ csr_src,
                                                   const float* __restrict__ csr_norm,
                                                   short* __restrict__ axh,
                                                   short* __restrict__ axl) {
    int wave = threadIdx.x >> 6;
    int lane = threadIdx.x & 63;
    int n = blockIdx.x * 4 + wave;
    bool act = lane < NF4;
    int lo4 = act ? lane * 4 : 0;                  // inactive lanes read row start (safe)
    float di = dinv[n];
    float sw = di * di;
    short4 sv = *(const short4*)(xb + (size_t)n * IN_F + lo4);
    float ax = sw * bf2f(sv.x), ay = sw * bf2f(sv.y);
    float az = sw * bf2f(sv.z), aw = sw * bf2f(sv.w);

    int p0 = offs[n], p1 = offs[n + 1];
    int p = p0;
    for (; p + 8 <= p1; p += 8) {
        int   s[8]; float w[8]; short4 r[8];
        #pragma unroll
        for (int j = 0; j < 8; ++j) { s[j] = csr_src[p + j]; w[j] = csr_norm[p + j]; }
        #pragma unroll
        for (int j = 0; j < 8; ++j) r[j] = *(const short4*)(xb + (size_t)s[j] * IN_F + lo4);
        #pragma unroll
        for (int j = 0; j < 8; ++j) {
            ax += w[j] * bf2f(r[j].x); ay += w[j] * bf2f(r[j].y);
            az += w[j] * bf2f(r[j].z); aw += w[j] * bf2f(r[j].w);
        }
    }
    for (; p + 4 <= p1; p += 4) {
        int   s[4]; float w[4]; short4 r[4];
        #pragma unroll
        for (int j = 0; j < 4; ++j) { s[j] = csr_src[p + j]; w[j] = csr_norm[p + j]; }
        #pragma unroll
        for (int j = 0; j < 4; ++j) r[j] = *(const short4*)(xb + (size_t)s[j] * IN_F + lo4);
        #pragma unroll
        for (int j = 0; j < 4; ++j) {
            ax += w[j] * bf2f(r[j].x); ay += w[j] * bf2f(r[j].y);
            az += w[j] * bf2f(r[j].z); aw += w[j] * bf2f(r[j].w);
        }
    }
    for (; p < p1; ++p) {
        int   s0 = csr_src[p];
        float w0 = csr_norm[p];
        short4 r0 = *(const short4*)(xb + (size_t)s0 * IN_F + lo4);
        ax += w0 * bf2f(r0.x); ay += w0 * bf2f(r0.y);
        az += w0 * bf2f(r0.z); aw += w0 * bf2f(r0.w);
    }

    size_t base = (size_t)n * K1P + lane * 4;
    if (act) {
        float a[4] = {ax, ay, az, aw};
        short hv[4], lv[4];
        #pragma unroll
        for (int i = 0; i < 4; ++i) {
            hv[i] = f2bf(a[i]);
            lv[i] = f2bf(a[i] - bf2f(hv[i]));
        }
        *(short4*)&axh[base] = make_short4(hv[0], hv[1], hv[2], hv[3]);
        *(short4*)&axl[base] = make_short4(lv[0], lv[1], lv[2], lv[3]);
    } else if (lane < 48) {                        // zero pad cols 168..191
        short4 z = make_short4(0, 0, 0, 0);
        *(short4*)&axh[base] = z;
        *(short4*)&axl[base] = z;
    }
}

// layer 2: agg from bf16 h1 rows (512B); one short4 per lane; 8-deep ILP.
__global__ __launch_bounds__(256) void agg_h_split(const short* __restrict__ h1h,
                                                   const float* __restrict__ dinv,
                                                   const int* __restrict__ offs,
                                                   const int* __restrict__ csr_src,
                                                   const float* __restrict__ csr_norm,
                                                   short* __restrict__ ahh,
                                                   short* __restrict__ ahl) {
    int wave = threadIdx.x >> 6;
    int lane = threadIdx.x & 63;
    int n = blockIdx.x * 4 + wave;
    int lo4 = lane * 4;
    float di = dinv[n];
    float sw = di * di;
    short4 sv = *(const short4*)(h1h + (size_t)n * HID + lo4);
    float ax = sw * bf2f(sv.x), ay = sw * bf2f(sv.y);
    float az = sw * bf2f(sv.z), aw = sw * bf2f(sv.w);

    int p0 = offs[n], p1 = offs[n + 1];
    int p = p0;
    for (; p + 8 <= p1; p += 8) {
        int   s[8]; float w[8]; short4 r[8];
        #pragma unroll
        for (int j = 0; j < 8; ++j) { s[j] = csr_src[p + j]; w[j] = csr_norm[p + j]; }
        #pragma unroll
        for (int j = 0; j < 8; ++j) r[j] = *(const short4*)(h1h + (size_t)s[j] * HID + lo4);
        #pragma unroll
        for (int j = 0; j < 8; ++j) {
            ax += w[j] * bf2f(r[j].x); ay += w[j] * bf2f(r[j].y);
            az += w[j] * bf2f(r[j].z); aw += w[j] * bf2f(r[j].w);
        }
    }
    for (; p + 4 <= p1; p += 4) {
        int   s[4]; float w[4]; short4 r[4];
        #pragma unroll
        for (int j = 0; j < 4; ++j) { s[j] = csr_src[p + j]; w[j] = csr_norm[p + j]; }
        #pragma unroll
        for (int j = 0; j < 4; ++j) r[j] = *(const short4*)(h1h + (size_t)s[j] * HID + lo4);
        #pragma unroll
        for (int j = 0; j < 4; ++j) {
            ax += w[j] * bf2f(r[j].x); ay += w[j] * bf2f(r[j].y);
            az += w[j] * bf2f(r[j].z); aw += w[j] * bf2f(r[j].w);
        }
    }
    for (; p < p1; ++p) {
        int   s0 = csr_src[p];
        float w0 = csr_norm[p];
        short4 r0 = *(const short4*)(h1h + (size_t)s0 * HID + lo4);
        ax += w0 * bf2f(r0.x); ay += w0 * bf2f(r0.y);
        az += w0 * bf2f(r0.z); aw += w0 * bf2f(r0.w);
    }

    float a[4] = {ax, ay, az, aw};
    short hv[4], lv[4];
    #pragma unroll
    for (int i = 0; i < 4; ++i) {
        hv[i] = f2bf(a[i]);
        lv[i] = f2bf(a[i] - bf2f(hv[i]));
    }
    size_t base = (size_t)n * HID + lo4;
    *(short4*)&ahh[base] = make_short4(hv[0], hv[1], hv[2], hv[3]);
    *(short4*)&ahl[base] = make_short4(lv[0], lv[1], lv[2], lv[3]);
}

// ---------------- MFMA GEMM with fused bias+ReLU epilogue ----------------
// C[M,256] = relu(A[M,K] * W[256,K]^T + bias). Split-bf16 3-product.
// 64x64 tile, 4 waves each 32x32 (2x2 MFMA 16x16x32), BK=64, LDS-staged,
// register prefetch. mode 0: store bf16-hi to Cbf; mode 1: store fp32 to Cf.

#define LDS_STRIDE 72

__global__ __launch_bounds__(256) void gemm_split(const short* __restrict__ Ah,
                                                  const short* __restrict__ Al,
                                                  const short* __restrict__ Wh,
                                                  const short* __restrict__ Wl,
                                                  const float* __restrict__ bias,
                                                  float* __restrict__ Cf,
                                                  short* __restrict__ Cbf,
                                                  int M, int Ks, int nsteps, int mode) {
    __shared__ short sAh[64 * LDS_STRIDE];
    __shared__ short sAl[64 * LDS_STRIDE];
    __shared__ short sWh[64 * LDS_STRIDE];
    __shared__ short sWl[64 * LDS_STRIDE];

    const int tid  = threadIdx.x;
    const int lane = tid & 63;
    const int wv   = tid >> 6;
    const int l16  = lane & 15;
    const int quad = lane >> 4;
    const int wm   = (wv & 1) * 32;
    const int wn   = (wv >> 1) * 32;
    const int bm   = blockIdx.x * 64;
    const int bn   = blockIdx.y * 64;

    const int srow = tid >> 2;
    const int sseg = (tid & 3) * 16;
    int arow = bm + srow; if (arow >= M) arow = M - 1;
    const short* gAh = Ah + (size_t)arow * Ks;
    const short* gAl = Al + (size_t)arow * Ks;
    const short* gWh = Wh + (size_t)(bn + srow) * Ks;
    const short* gWl = Wl + (size_t)(bn + srow) * Ks;
    const int lds_off = srow * LDS_STRIDE + sseg;

    f32x4 acc00 = {0,0,0,0}, acc01 = {0,0,0,0}, acc10 = {0,0,0,0}, acc11 = {0,0,0,0};

    int4 pah0 = *(const int4*)(gAh + sseg), pah1 = *(const int4*)(gAh + sseg + 8);
    int4 pal0 = *(const int4*)(gAl + sseg), pal1 = *(const int4*)(gAl + sseg + 8);
    int4 pwh0 = *(const int4*)(gWh + sseg), pwh1 = *(const int4*)(gWh + sseg + 8);
    int4 pwl0 = *(const int4*)(gWl + sseg), pwl1 = *(const int4*)(gWl + sseg + 8);

    for (int ks = 0; ks < nsteps; ++ks) {
        *(int4*)&sAh[lds_off] = pah0; *(int4*)&sAh[lds_off + 8] = pah1;
        *(int4*)&sAl[lds_off] = pal0; *(int4*)&sAl[lds_off + 8] = pal1;
        *(int4*)&sWh[lds_off] = pwh0; *(int4*)&sWh[lds_off + 8] = pwh1;
        *(int4*)&sWl[lds_off] = pwl0; *(int4*)&sWl[lds_off + 8] = pwl1;
        __syncthreads();
        if (ks + 1 < nsteps) {
            int o = (ks + 1) * 64 + sseg;
            pah0 = *(const int4*)(gAh + o); pah1 = *(const int4*)(gAh + o + 8);
            pal0 = *(const int4*)(gAl + o); pal1 = *(const int4*)(gAl + o + 8);
            pwh0 = *(const int4*)(gWh + o); pwh1 = *(const int4*)(gWh + o + 8);
            pwl0 = *(const int4*)(gWl + o); pwl1 = *(const int4*)(gWl + o + 8);
        }
        #pragma unroll
        for (int o = 0; o < 2; ++o) {
            const int a0 = (wm + l16) * LDS_STRIDE + o * 32 + quad * 8;
            const int a1 = a0 + 16 * LDS_STRIDE;
            const int w0 = (wn + l16) * LDS_STRIDE + o * 32 + quad * 8;
            const int w1 = w0 + 16 * LDS_STRIDE;
            bf16x8 ah0 = *(const bf16x8*)&sAh[a0];
            bf16x8 ah1 = *(const bf16x8*)&sAh[a1];
            bf16x8 al0 = *(const bf16x8*)&sAl[a0];
            bf16x8 al1 = *(const bf16x8*)&sAl[a1];
            bf16x8 wh0 = *(const bf16x8*)&sWh[w0];
            bf16x8 wh1 = *(const bf16x8*)&sWh[w1];
            bf16x8 wl0 = *(const bf16x8*)&sWl[w0];
            bf16x8 wl1 = *(const bf16x8*)&sWl[w1];
            acc00 = __builtin_amdgcn_mfma_f32_16x16x32_bf16(ah0, wh0, acc00, 0, 0, 0);
            acc00 = __builtin_amdgcn_mfma_f32_16x16x32_bf16(ah0, wl0, acc00, 0, 0, 0);
            acc00 = __builtin_amdgcn_mfma_f32_16x16x32_bf16(al0, wh0, acc00, 0, 0, 0);
            acc01 = __builtin_amdgcn_mfma_f32_16x16x32_bf16(ah0, wh1, acc01, 0, 0, 0);
            acc01 = __builtin_amdgcn_mfma_f32_16x16x32_bf16(ah0, wl1, acc01, 0, 0, 0);
            acc01 = __builtin_amdgcn_mfma_f32_16x16x32_bf16(al0, wh1, acc01, 0, 0, 0);
            acc10 = __builtin_amdgcn_mfma_f32_16x16x32_bf16(ah1, wh0, acc10, 0, 0, 0);
            acc10 = __builtin_amdgcn_mfma_f32_16x16x32_bf16(ah1, wl0, acc10, 0, 0, 0);
            acc10 = __builtin_amdgcn_mfma_f32_16x16x32_bf16(al1, wh0, acc10, 0, 0, 0);
            acc11 = __builtin_amdgcn_mfma_f32_16x16x32_bf16(ah1, wh1, acc11, 0, 0, 0);
            acc11 = __builtin_amdgcn_mfma_f32_16x16x32_bf16(ah1, wl1, acc11, 0, 0, 0);
            acc11 = __builtin_amdgcn_mfma_f32_16x16x32_bf16(al1, wh1, acc11, 0, 0, 0);
        }
        __syncthreads();
    }

    const int colb = bn + wn + l16;
    const int rowb = bm + wm + quad * 4;
    const float b0 = bias[colb];
    const float b1 = bias[colb + 16];
    #pragma unroll
    for (int r = 0; r < 4; ++r) {
        int row = rowb + r;
        if (row < M) {
            float v0 = acc00[r] + b0; v0 = v0 > 0.f ? v0 : 0.f;
            float v1 = acc01[r] + b1; v1 = v1 > 0.f ? v1 : 0.f;
            if (mode == 0) {
                Cbf[(size_t)row * HID + colb]      = f2bf(v0);
                Cbf[(size_t)row * HID + colb + 16] = f2bf(v1);
            } else {
                Cf[(size_t)row * HID + colb]      = v0;
                Cf[(size_t)row * HID + colb + 16] = v1;
            }
        }
        int row2 = row + 16;
        if (row2 < M) {
            float v0 = acc10[r] + b0; v0 = v0 > 0.f ? v0 : 0.f;
            float v1 = acc11[r] + b1; v1 = v1 > 0.f ? v1 : 0.f;
            if (mode == 0) {
                Cbf[(size_t)row2 * HID + colb]      = f2bf(v0);
                Cbf[(size_t)row2 * HID + colb + 16] = f2bf(v1);
            } else {
                Cf[(size_t)row2 * HID + colb]      = v0;
                Cf[(size_t)row2 * HID + colb + 16] = v1;
            }
        }
    }
}

// ---------------- launch ----------------

extern "C" void kernel_launch(void* const* d_in, const int* in_sizes, int n_in,
                              void* d_out, int out_size, void* d_ws, size_t ws_size,
                              hipStream_t stream) {
    const float* x  = (const float*)d_in[0];
    const int*   ei = (const int*)d_in[1];
    const float* ew = (const float*)d_in[2];
    const float* W1 = (const float*)d_in[3];
    const float* b1 = (const float*)d_in[4];
    const float* W2 = (const float*)d_in[5];
    const float* b2 = (const float*)d_in[6];
    float* out = (float*)d_out;

    char* ws = (char*)d_ws;
    float* deg      = (float*)(ws);                 // 20000 f32 (becomes dinv)
    int*   counts   = (int*)(ws + 80000);           // 20000 i32
    int*   cursor   = (int*)(ws + 160000);          // 20000 i32
    int*   offs     = (int*)(ws + 240000);          // 20001 i32
    int*   bsum     = (int*)(ws + 320016);          // 20 i32 (pad to 320144)
    int*   csr_src  = (int*)(ws + 320144);          // 320000 i32 -> 1600144
    float* csr_norm = (float*)(ws + 1600144);       // 320000 f32 -> 2880144
    // region A: agg_x split (2 x 20000x192 bf16 = 15.36MB), dead after gemm1;
    // reused for agg_h split (2 x 20000x256 bf16 = 20.48MB)
    short* axh      = (short*)(ws + 2880144);       // -> 10560144
    short* axl      = (short*)(ws + 10560144);      // -> 18240144
    short* ahh      = (short*)(ws + 2880144);       // -> 13120144
    short* ahl      = (short*)(ws + 13120144);      // -> 23360144
    short* h1h      = (short*)(ws + 23360144);      // 20000x256 bf16 -> 33600144
    short* w1h      = (short*)(ws + 33600144);      // 256x192 -> 33698448
    short* w1l      = (short*)(ws + 33698448);      // -> 33796752
    short* w2h      = (short*)(ws + 33796752);      // 256x256 -> 33927824
    short* w2l      = (short*)(ws + 33927824);      // -> 34058896
    short* xb       = (short*)(ws + 34058896);      // 20000x168 bf16 -> 40778896

    hipMemsetAsync(d_ws, 0, 240000, stream);        // deg, counts, cursor

    const int TB = 256;
    edge_count_deg<<<(N_EDGES + TB - 1) / TB, TB, 0, stream>>>(ei, ew, deg, counts);
    scan_part<<<20, 1024, 0, stream>>>(counts, offs, bsum, deg, N_NODES);
    scan_add<<<20, 1024, 0, stream>>>(bsum, offs, N_NODES);
    scatter_edges<<<(N_EDGES + TB - 1) / TB, TB, 0, stream>>>(ei, ew, deg, offs, cursor,
                                                              csr_src, csr_norm);
    conv_x<<<(N_NODES * IN_F / 4 + TB - 1) / TB, TB, 0, stream>>>(x, xb);
    split_w<<<512, 256, 0, stream>>>(W1, W2, w1h, w1l, w2h, w2l);

    dim3 gg((N_NODES + 63) / 64, 4);
    // layer 1: Agg(bf16 x) -> split; GEMM(+b1, ReLU) -> h1 bf16-hi
    agg_x_split<<<N_NODES / 4, 256, 0, stream>>>(xb, deg, offs, csr_src, csr_norm, axh, axl);
    gemm_split<<<gg, 256, 0, stream>>>(axh, axl, w1h, w1l, b1, nullptr, h1h,
                                       N_NODES, K1P, 3, 0);
    // layer 2: Agg(bf16 h1) -> split; GEMM(+b2, ReLU) -> out fp32
    agg_h_split<<<N_NODES / 4, 256, 0, stream>>>(h1h, deg, offs, csr_src, csr_norm, ahh, ahl);
    gemm_split<<<gg, 256, 0, stream>>>(ahh, ahl, w2h, w2l, b2, out, nullptr,
                                       N_NODES, HID, 4, 1);
}

// Round 10
// 217.633 us; speedup vs baseline: 2.9191x; 1.0594x over previous
//
#include <hip/hip_runtime.h>

#define N_NODES 20000
#define N_EDGES 320000
#define IN_F    168
#define HID     256
#define K1P     192   // IN_F zero-padded to multiple of 64
#define NF4     42    // IN_F / 4

typedef __attribute__((ext_vector_type(8))) short bf16x8;
typedef __attribute__((ext_vector_type(4))) float f32x4;

__device__ __forceinline__ short f2bf(float f) {
    union { float f; unsigned u; } v; v.f = f;
    unsigned r = v.u + 0x7FFFu + ((v.u >> 16) & 1u);
    return (short)(r >> 16);
}
__device__ __forceinline__ float bf2f(short s) {
    union { unsigned u; float f; } v; v.u = ((unsigned)(unsigned short)s) << 16;
    return v.f;
}

// ---------------- graph prep ----------------

__global__ void edge_count_deg(const int* __restrict__ ei, const float* __restrict__ ew,
                               float* __restrict__ deg, int* __restrict__ counts) {
    int e = blockIdx.x * blockDim.x + threadIdx.x;
    if (e >= N_EDGES) return;
    int d = ei[N_EDGES + e];
    atomicAdd(&deg[d], ew[e]);
    atomicAdd(&counts[d], 1);
}

// two-kernel parallel scan: part (block-local exclusive + block totals, dinv fold)
__global__ __launch_bounds__(1024) void scan_part(const int* __restrict__ counts,
                                                  int* __restrict__ offs,
                                                  int* __restrict__ bsum,
                                                  float* __restrict__ deg, int n) {
    int tid  = threadIdx.x;
    int lane = tid & 63;
    int wv   = tid >> 6;
    int i = blockIdx.x * 1024 + tid;
    if (i < n) deg[i] = rsqrtf(deg[i] + 1.0f);     // self-loop weight 1.0
    __shared__ int wsum[16];
    int v = (i < n) ? counts[i] : 0;
    int incl = v;
    #pragma unroll
    for (int d = 1; d < 64; d <<= 1) {
        int t = __shfl_up(incl, d);
        if (lane >= d) incl += t;
    }
    if (lane == 63) wsum[wv] = incl;
    __syncthreads();
    if (wv == 0) {
        int w = (lane < 16) ? wsum[lane] : 0;
        int winc = w;
        #pragma unroll
        for (int d = 1; d < 16; d <<= 1) {
            int t = __shfl_up(winc, d);
            if (lane >= d) winc += t;
        }
        if (lane < 16) wsum[lane] = winc - w;      // exclusive wave offsets
    }
    __syncthreads();
    if (i < n) offs[i] = wsum[wv] + incl - v;      // block-local exclusive
    if (tid == 1023) bsum[blockIdx.x] = wsum[15] + incl;
}

__global__ __launch_bounds__(1024) void scan_add(const int* __restrict__ bsum,
                                                 int* __restrict__ offs, int n) {
    int i = blockIdx.x * 1024 + threadIdx.x;
    int add = 0;
    for (int b = 0; b < (int)blockIdx.x; ++b) add += bsum[b];
    if (i < n) offs[i] += add;
    if (i == n) offs[n] = add + bsum[blockIdx.x];
}

__global__ void scatter_edges(const int* __restrict__ ei, const float* __restrict__ ew,
                              const float* __restrict__ dinv, const int* __restrict__ offs,
                              int* __restrict__ cursor, int* __restrict__ csr_src,
                              float* __restrict__ csr_norm) {
    int e = blockIdx.x * blockDim.x + threadIdx.x;
    if (e >= N_EDGES) return;
    int s = ei[e];
    int d = ei[N_EDGES + e];
    int pos = offs[d] + atomicAdd(&cursor[d], 1);
    csr_src[pos]  = s;
    csr_norm[pos] = dinv[s] * ew[e] * dinv[d];
}

// ---------------- fused conversions: x -> bf16; W1/W2 -> split bf16 ----------------
// blocks [0, XB4): conv x (float4 -> short4)
// blocks [XB4, XB4+512): weight split (W1 rows 0..255 padded to 192; W2 rows 256..511)

#define XB4 3282   // ceil(840000 / 256)

__global__ void prep_convert(const float* __restrict__ x, short* __restrict__ xb,
                             const float* __restrict__ W1, const float* __restrict__ W2,
                             short* __restrict__ w1h, short* __restrict__ w1l,
                             short* __restrict__ w2h, short* __restrict__ w2l) {
    int b = blockIdx.x;
    if (b < XB4) {
        int i = b * 256 + threadIdx.x;
        const int n4 = (N_NODES * IN_F) / 4;            // 840000
        if (i >= n4) return;
        float4 v = *(const float4*)(x + (size_t)i * 4);
        *(short4*)(xb + (size_t)i * 4) =
            make_short4(f2bf(v.x), f2bf(v.y), f2bf(v.z), f2bf(v.w));
        return;
    }
    int r = b - XB4;
    int k = threadIdx.x;
    if (r < 256) {
        if (k >= K1P) return;
        float v = (k < IN_F) ? W1[(size_t)r * IN_F + k] : 0.f;
        short h = f2bf(v);
        w1h[(size_t)r * K1P + k] = h;
        w1l[(size_t)r * K1P + k] = f2bf(v - bf2f(h));
    } else {
        int r2 = r - 256;
        float v = W2[(size_t)r2 * HID + k];
        short h = f2bf(v);
        w2h[(size_t)r2 * HID + k] = h;
        w2l[(size_t)r2 * HID + k] = f2bf(v - bf2f(h));
    }
}

// ---------------- gathers (Agg BEFORE GEMM; emit split-bf16 A operand) ----------

// layer 1: agg from bf16 x rows (336B); wave per node, lanes 0..41 own short4.
__global__ __launch_bounds__(256) void agg_x_split(const short* __restrict__ xb,
                                                   const float* __restrict__ dinv,
                                                   const int* __restrict__ offs,
                                                   const int* __restrict__ csr_src,
                                                   const float* __restrict__ csr_norm,
                                                   short* __restrict__ axh,
                                                   short* __restrict__ axl) {
    int wave = threadIdx.x >> 6;
    int lane = threadIdx.x & 63;
    int n = blockIdx.x * 4 + wave;
    bool act = lane < NF4;
    int lo4 = act ? lane * 4 : 0;                  // inactive lanes read row start (safe)
    float di = dinv[n];
    float sw = di * di;
    short4 sv = *(const short4*)(xb + (size_t)n * IN_F + lo4);
    float ax = sw * bf2f(sv.x), ay = sw * bf2f(sv.y);
    float az = sw * bf2f(sv.z), aw = sw * bf2f(sv.w);

    int p0 = offs[n], p1 = offs[n + 1];
    int p = p0;
    for (; p + 8 <= p1; p += 8) {
        int   s[8]; float w[8]; short4 r[8];
        #pragma unroll
        for (int j = 0; j < 8; ++j) { s[j] = csr_src[p + j]; w[j] = csr_norm[p + j]; }
        #pragma unroll
        for (int j = 0; j < 8; ++j) r[j] = *(const short4*)(xb + (size_t)s[j] * IN_F + lo4);
        #pragma unroll
        for (int j = 0; j < 8; ++j) {
            ax += w[j] * bf2f(r[j].x); ay += w[j] * bf2f(r[j].y);
            az += w[j] * bf2f(r[j].z); aw += w[j] * bf2f(r[j].w);
        }
    }
    for (; p + 4 <= p1; p += 4) {
        int   s[4]; float w[4]; short4 r[4];
        #pragma unroll
        for (int j = 0; j < 4; ++j) { s[j] = csr_src[p + j]; w[j] = csr_norm[p + j]; }
        #pragma unroll
        for (int j = 0; j < 4; ++j) r[j] = *(const short4*)(xb + (size_t)s[j] * IN_F + lo4);
        #pragma unroll
        for (int j = 0; j < 4; ++j) {
            ax += w[j] * bf2f(r[j].x); ay += w[j] * bf2f(r[j].y);
            az += w[j] * bf2f(r[j].z); aw += w[j] * bf2f(r[j].w);
        }
    }
    for (; p < p1; ++p) {
        int   s0 = csr_src[p];
        float w0 = csr_norm[p];
        short4 r0 = *(const short4*)(xb + (size_t)s0 * IN_F + lo4);
        ax += w0 * bf2f(r0.x); ay += w0 * bf2f(r0.y);
        az += w0 * bf2f(r0.z); aw += w0 * bf2f(r0.w);
    }

    size_t base = (size_t)n * K1P + lane * 4;
    if (act) {
        float a[4] = {ax, ay, az, aw};
        short hv[4], lv[4];
        #pragma unroll
        for (int i = 0; i < 4; ++i) {
            hv[i] = f2bf(a[i]);
            lv[i] = f2bf(a[i] - bf2f(hv[i]));
        }
        *(short4*)&axh[base] = make_short4(hv[0], hv[1], hv[2], hv[3]);
        *(short4*)&axl[base] = make_short4(lv[0], lv[1], lv[2], lv[3]);
    } else if (lane < 48) {                        // zero pad cols 168..191
        short4 z = make_short4(0, 0, 0, 0);
        *(short4*)&axh[base] = z;
        *(short4*)&axl[base] = z;
    }
}

// layer 2: agg from bf16 h1 rows (512B); one short4 per lane; 8-deep ILP.
__global__ __launch_bounds__(256) void agg_h_split(const short* __restrict__ h1h,
                                                   const float* __restrict__ dinv,
                                                   const int* __restrict__ offs,
                                                   const int* __restrict__ csr_src,
                                                   const float* __restrict__ csr_norm,
                                                   short* __restrict__ ahh,
                                                   short* __restrict__ ahl) {
    int wave = threadIdx.x >> 6;
    int lane = threadIdx.x & 63;
    int n = blockIdx.x * 4 + wave;
    int lo4 = lane * 4;
    float di = dinv[n];
    float sw = di * di;
    short4 sv = *(const short4*)(h1h + (size_t)n * HID + lo4);
    float ax = sw * bf2f(sv.x), ay = sw * bf2f(sv.y);
    float az = sw * bf2f(sv.z), aw = sw * bf2f(sv.w);

    int p0 = offs[n], p1 = offs[n + 1];
    int p = p0;
    for (; p + 8 <= p1; p += 8) {
        int   s[8]; float w[8]; short4 r[8];
        #pragma unroll
        for (int j = 0; j < 8; ++j) { s[j] = csr_src[p + j]; w[j] = csr_norm[p + j]; }
        #pragma unroll
        for (int j = 0; j < 8; ++j) r[j] = *(const short4*)(h1h + (size_t)s[j] * HID + lo4);
        #pragma unroll
        for (int j = 0; j < 8; ++j) {
            ax += w[j] * bf2f(r[j].x); ay += w[j] * bf2f(r[j].y);
            az += w[j] * bf2f(r[j].z); aw += w[j] * bf2f(r[j].w);
        }
    }
    for (; p + 4 <= p1; p += 4) {
        int   s[4]; float w[4]; short4 r[4];
        #pragma unroll
        for (int j = 0; j < 4; ++j) { s[j] = csr_src[p + j]; w[j] = csr_norm[p + j]; }
        #pragma unroll
        for (int j = 0; j < 4; ++j) r[j] = *(const short4*)(h1h + (size_t)s[j] * HID + lo4);
        #pragma unroll
        for (int j = 0; j < 4; ++j) {
            ax += w[j] * bf2f(r[j].x); ay += w[j] * bf2f(r[j].y);
            az += w[j] * bf2f(r[j].z); aw += w[j] * bf2f(r[j].w);
        }
    }
    for (; p < p1; ++p) {
        int   s0 = csr_src[p];
        float w0 = csr_norm[p];
        short4 r0 = *(const short4*)(h1h + (size_t)s0 * HID + lo4);
        ax += w0 * bf2f(r0.x); ay += w0 * bf2f(r0.y);
        az += w0 * bf2f(r0.z); aw += w0 * bf2f(r0.w);
    }

    float a[4] = {ax, ay, az, aw};
    short hv[4], lv[4];
    #pragma unroll
    for (int i = 0; i < 4; ++i) {
        hv[i] = f2bf(a[i]);
        lv[i] = f2bf(a[i] - bf2f(hv[i]));
    }
    size_t base = (size_t)n * HID + lo4;
    *(short4*)&ahh[base] = make_short4(hv[0], hv[1], hv[2], hv[3]);
    *(short4*)&ahl[base] = make_short4(lv[0], lv[1], lv[2], lv[3]);
}

// ---------------- MFMA GEMM with fused bias+ReLU epilogue ----------------
// C[M,256] = relu(A[M,K] * W[256,K]^T + bias). Split-bf16 3-product.
// 64x64 tile, 4 waves each 32x32 (2x2 MFMA 16x16x32), BK=64, LDS-staged,
// register prefetch. XCD-affinity swizzle: the 4 nt-siblings of one mt are
// placed at block indices congruent mod 8 (same XCD under RR dispatch) so the
// A-tile is fetched from LLC once per mt and re-served from that XCD's L2.
// mode 0: store bf16-hi to Cbf; mode 1: store fp32 to Cf.

#define LDS_STRIDE 72

__global__ __launch_bounds__(256) void gemm_split(const short* __restrict__ Ah,
                                                  const short* __restrict__ Al,
                                                  const short* __restrict__ Wh,
                                                  const short* __restrict__ Wl,
                                                  const float* __restrict__ bias,
                                                  float* __restrict__ Cf,
                                                  short* __restrict__ Cbf,
                                                  int M, int Ks, int nsteps, int mode) {
    __shared__ short sAh[64 * LDS_STRIDE];
    __shared__ short sAl[64 * LDS_STRIDE];
    __shared__ short sWh[64 * LDS_STRIDE];
    __shared__ short sWl[64 * LDS_STRIDE];

    // swizzle: idx = group*32 + slot*8 + xcd  ->  mt = group*8 + xcd, nt = slot
    const int idx   = blockIdx.x;
    const int group = idx >> 5;
    const int xcd   = idx & 7;
    const int slot  = (idx >> 3) & 3;
    const int mt    = group * 8 + xcd;
    const int mtiles = (M + 63) >> 6;
    if (mt >= mtiles) return;
    const int bm = mt * 64;
    const int bn = slot * 64;

    const int tid  = threadIdx.x;
    const int lane = tid & 63;
    const int wv   = tid >> 6;
    const int l16  = lane & 15;
    const int quad = lane >> 4;
    const int wm   = (wv & 1) * 32;
    const int wn   = (wv >> 1) * 32;

    const int srow = tid >> 2;
    const int sseg = (tid & 3) * 16;
    int arow = bm + srow; if (arow >= M) arow = M - 1;
    const short* gAh = Ah + (size_t)arow * Ks;
    const short* gAl = Al + (size_t)arow * Ks;
    const short* gWh = Wh + (size_t)(bn + srow) * Ks;
    const short* gWl = Wl + (size_t)(bn + srow) * Ks;
    const int lds_off = srow * LDS_STRIDE + sseg;

    f32x4 acc00 = {0,0,0,0}, acc01 = {0,0,0,0}, acc10 = {0,0,0,0}, acc11 = {0,0,0,0};

    int4 pah0 = *(const int4*)(gAh + sseg), pah1 = *(const int4*)(gAh + sseg + 8);
    int4 pal0 = *(const int4*)(gAl + sseg), pal1 = *(const int4*)(gAl + sseg + 8);
    int4 pwh0 = *(const int4*)(gWh + sseg), pwh1 = *(const int4*)(gWh + sseg + 8);
    int4 pwl0 = *(const int4*)(gWl + sseg), pwl1 = *(const int4*)(gWl + sseg + 8);

    for (int ks = 0; ks < nsteps; ++ks) {
        *(int4*)&sAh[lds_off] = pah0; *(int4*)&sAh[lds_off + 8] = pah1;
        *(int4*)&sAl[lds_off] = pal0; *(int4*)&sAl[lds_off + 8] = pal1;
        *(int4*)&sWh[lds_off] = pwh0; *(int4*)&sWh[lds_off + 8] = pwh1;
        *(int4*)&sWl[lds_off] = pwl0; *(int4*)&sWl[lds_off + 8] = pwl1;
        __syncthreads();
        if (ks + 1 < nsteps) {
            int o = (ks + 1) * 64 + sseg;
            pah0 = *(const int4*)(gAh + o); pah1 = *(const int4*)(gAh + o + 8);
            pal0 = *(const int4*)(gAl + o); pal1 = *(const int4*)(gAl + o + 8);
            pwh0 = *(const int4*)(gWh + o); pwh1 = *(const int4*)(gWh + o + 8);
            pwl0 = *(const int4*)(gWl + o); pwl1 = *(const int4*)(gWl + o + 8);
        }
        #pragma unroll
        for (int o = 0; o < 2; ++o) {
            const int a0 = (wm + l16) * LDS_STRIDE + o * 32 + quad * 8;
            const int a1 = a0 + 16 * LDS_STRIDE;
            const int w0 = (wn + l16) * LDS_STRIDE + o * 32 + quad * 8;
            const int w1 = w0 + 16 * LDS_STRIDE;
            bf16x8 ah0 = *(const bf16x8*)&sAh[a0];
            bf16x8 ah1 = *(const bf16x8*)&sAh[a1];
            bf16x8 al0 = *(const bf16x8*)&sAl[a0];
            bf16x8 al1 = *(const bf16x8*)&sAl[a1];
            bf16x8 wh0 = *(const bf16x8*)&sWh[w0];
            bf16x8 wh1 = *(const bf16x8*)&sWh[w1];
            bf16x8 wl0 = *(const bf16x8*)&sWl[w0];
            bf16x8 wl1 = *(const bf16x8*)&sWl[w1];
            acc00 = __builtin_amdgcn_mfma_f32_16x16x32_bf16(ah0, wh0, acc00, 0, 0, 0);
            acc00 = __builtin_amdgcn_mfma_f32_16x16x32_bf16(ah0, wl0, acc00, 0, 0, 0);
            acc00 = __builtin_amdgcn_mfma_f32_16x16x32_bf16(al0, wh0, acc00, 0, 0, 0);
            acc01 = __builtin_amdgcn_mfma_f32_16x16x32_bf16(ah0, wh1, acc01, 0, 0, 0);
            acc01 = __builtin_amdgcn_mfma_f32_16x16x32_bf16(ah0, wl1, acc01, 0, 0, 0);
            acc01 = __builtin_amdgcn_mfma_f32_16x16x32_bf16(al0, wh1, acc01, 0, 0, 0);
            acc10 = __builtin_amdgcn_mfma_f32_16x16x32_bf16(ah1, wh0, acc10, 0, 0, 0);
            acc10 = __builtin_amdgcn_mfma_f32_16x16x32_bf16(ah1, wl0, acc10, 0, 0, 0);
            acc10 = __builtin_amdgcn_mfma_f32_16x16x32_bf16(al1, wh0, acc10, 0, 0, 0);
            acc11 = __builtin_amdgcn_mfma_f32_16x16x32_bf16(ah1, wh1, acc11, 0, 0, 0);
            acc11 = __builtin_amdgcn_mfma_f32_16x16x32_bf16(ah1, wl1, acc11, 0, 0, 0);
            acc11 = __builtin_amdgcn_mfma_f32_16x16x32_bf16(al1, wh1, acc11, 0, 0, 0);
        }
        __syncthreads();
    }

    const int colb = bn + wn + l16;
    const int rowb = bm + wm + quad * 4;
    const float b0 = bias[colb];
    const float b1 = bias[colb + 16];
    #pragma unroll
    for (int r = 0; r < 4; ++r) {
        int row = rowb + r;
        if (row < M) {
            float v0 = acc00[r] + b0; v0 = v0 > 0.f ? v0 : 0.f;
            float v1 = acc01[r] + b1; v1 = v1 > 0.f ? v1 : 0.f;
            if (mode == 0) {
                Cbf[(size_t)row * HID + colb]      = f2bf(v0);
                Cbf[(size_t)row * HID + colb + 16] = f2bf(v1);
            } else {
                Cf[(size_t)row * HID + colb]      = v0;
                Cf[(size_t)row * HID + colb + 16] = v1;
            }
        }
        int row2 = row + 16;
        if (row2 < M) {
            float v0 = acc10[r] + b0; v0 = v0 > 0.f ? v0 : 0.f;
            float v1 = acc11[r] + b1; v1 = v1 > 0.f ? v1 : 0.f;
            if (mode == 0) {
                Cbf[(size_t)row2 * HID + colb]      = f2bf(v0);
                Cbf[(size_t)row2 * HID + colb + 16] = f2bf(v1);
            } else {
                Cf[(size_t)row2 * HID + colb]      = v0;
                Cf[(size_t)row2 * HID + colb + 16] = v1;
            }
        }
    }
}

// ---------------- launch ----------------

extern "C" void kernel_launch(void* const* d_in, const int* in_sizes, int n_in,
                              void* d_out, int out_size, void* d_ws, size_t ws_size,
                              hipStream_t stream) {
    const float* x  = (const float*)d_in[0];
    const int*   ei = (const int*)d_in[1];
    const float* ew = (const float*)d_in[2];
    const float* W1 = (const float*)d_in[3];
    const float* b1 = (const float*)d_in[4];
    const float* W2 = (const float*)d_in[5];
    const float* b2 = (const float*)d_in[6];
    float* out = (float*)d_out;

    char* ws = (char*)d_ws;
    float* deg      = (float*)(ws);                 // 20000 f32 (becomes dinv)
    int*   counts   = (int*)(ws + 80000);           // 20000 i32
    int*   cursor   = (int*)(ws + 160000);          // 20000 i32
    int*   offs     = (int*)(ws + 240000);          // 20001 i32
    int*   bsum     = (int*)(ws + 320016);          // 20 i32 (pad to 320144)
    int*   csr_src  = (int*)(ws + 320144);          // 320000 i32 -> 1600144
    float* csr_norm = (float*)(ws + 1600144);       // 320000 f32 -> 2880144
    // region A: agg_x split (2 x 20000x192 bf16 = 15.36MB), dead after gemm1;
    // reused for agg_h split (2 x 20000x256 bf16 = 20.48MB)
    short* axh      = (short*)(ws + 2880144);       // -> 10560144
    short* axl      = (short*)(ws + 10560144);      // -> 18240144
    short* ahh      = (short*)(ws + 2880144);       // -> 13120144
    short* ahl      = (short*)(ws + 13120144);      // -> 23360144
    short* h1h      = (short*)(ws + 23360144);      // 20000x256 bf16 -> 33600144
    short* w1h      = (short*)(ws + 33600144);      // 256x192 -> 33698448
    short* w1l      = (short*)(ws + 33698448);      // -> 33796752
    short* w2h      = (short*)(ws + 33796752);      // 256x256 -> 33927824
    short* w2l      = (short*)(ws + 33927824);      // -> 34058896
    short* xb       = (short*)(ws + 34058896);      // 20000x168 bf16 -> 40778896

    hipMemsetAsync(d_ws, 0, 240000, stream);        // deg, counts, cursor

    const int TB = 256;
    edge_count_deg<<<(N_EDGES + TB - 1) / TB, TB, 0, stream>>>(ei, ew, deg, counts);
    scan_part<<<20, 1024, 0, stream>>>(counts, offs, bsum, deg, N_NODES);
    scan_add<<<20, 1024, 0, stream>>>(bsum, offs, N_NODES);
    scatter_edges<<<(N_EDGES + TB - 1) / TB, TB, 0, stream>>>(ei, ew, deg, offs, cursor,
                                                              csr_src, csr_norm);
    prep_convert<<<XB4 + 512, 256, 0, stream>>>(x, xb, W1, W2, w1h, w1l, w2h, w2l);

    // swizzled grid: groups of 32 blocks = 8 mt (one per XCD) x 4 nt
    const int mtiles = (N_NODES + 63) / 64;          // 313
    const int gemm_grid = ((mtiles + 7) / 8) * 32;   // 1280
    // layer 1: Agg(bf16 x) -> split; GEMM(+b1, ReLU) -> h1 bf16-hi
    agg_x_split<<<N_NODES / 4, 256, 0, stream>>>(xb, deg, offs, csr_src, csr_norm, axh, axl);
    gemm_split<<<gemm_grid, 256, 0, stream>>>(axh, axl, w1h, w1l, b1, nullptr, h1h,
                                              N_NODES, K1P, 3, 0);
    // layer 2: Agg(bf16 h1) -> split; GEMM(+b2, ReLU) -> out fp32
    agg_h_split<<<N_NODES / 4, 256, 0, stream>>>(h1h, deg, offs, csr_src, csr_norm, ahh, ahl);
    gemm_split<<<gemm_grid, 256, 0, stream>>>(ahh, ahl, w2h, w2l, b2, out, nullptr,
                                              N_NODES, HID, 4, 1);
}